// Round 1
// 2200.451 us; speedup vs baseline: 1.2815x; 1.2815x over previous
//
#include <hip/hip_runtime.h>

#define O_N 2000
#define T_N 6000
#define DIN 2048
#define DW  300
#define DG  512
#define HH_ 512

typedef __attribute__((ext_vector_type(8)))  short short8;
typedef __attribute__((ext_vector_type(16))) float f32x16;
typedef unsigned short u16;

__device__ __forceinline__ float4 ld4(const float* p) { return *(const float4*)p; }

// ---- bf16 split-3 helpers (RNE) ----
__device__ __forceinline__ u16 rbf(float x) {
    unsigned int u = __float_as_uint(x);
    u += 0x7FFFu + ((u >> 16) & 1u);
    return (u16)(u >> 16);
}
__device__ __forceinline__ float fbf(u16 h) {
    return __uint_as_float((unsigned int)h << 16);
}
__device__ __forceinline__ void split3(float x, short& h, short& m, short& l) {
    u16 a = rbf(x);
    float r = x - fbf(a);
    u16 b = rbf(r);
    r -= fbf(b);
    u16 c = rbf(r);
    h = (short)a; m = (short)b; l = (short)c;
}

// =====================================================================
// MFMA GEMM: C = act(A @ B + bias) with A,B given as 3 bf16 planes
// (hi/mid/lo), chunk-major layout [K/8][Mp][8] (A) / [K/8][N][8] (B).
// 6 MFMA products: hh -> acc_hi ; hm, mh, hl, mm, lh -> acc_lo.
// Block 256 = 4 waves (2x2), wave tile 64 x (BN/2), 32x32x16 MFMA.
// Double-buffered LDS, one barrier per K=16 tile.
// Optional fp32 C out and/or bf16-plane out (for the next GEMM's A).
// Pair mode: gridDim.x doubled; bx >= nbx uses Bp2/C2/Op2.
// BN=64 used for grid-starved shapes: 2x blocks -> 2 blocks/CU.
// =====================================================================
template<int BM, int BN>
__global__ __launch_bounds__(256, 2) void gemm_mx(
    const u16* __restrict__ Ap, int MpA,
    const u16* __restrict__ Bp, int N, int KC, int M,
    const float* __restrict__ bias, int doRelu,
    float* __restrict__ C, int ldc,
    u16* __restrict__ Op, int MpO,
    const u16* __restrict__ Bp2, float* __restrict__ C2, u16* __restrict__ Op2,
    int nbx)
{
    static_assert(BM == 128, "BM=128");
    constexpr int WM = 64, WN = BN / 2;
    constexpr int FI = 2, FJ = WN / 32;
    constexpr int UA = 6 * BM;            // 16B staging units per tile (A)
    constexpr int UB = 6 * BN;
    constexpr int NI = (UA + UB) / 64;    // staging instructions per tile
    constexpr int II = (NI + 3) / 4;      // per wave
    constexpr int BUF = (BM + BN) * 48;   // ushorts per LDS buffer
    __shared__ u16 sm[2 * BUF];

    const int tid = threadIdx.x;
    const int w = tid >> 6, lane = tid & 63;
    const int ln31 = lane & 31, lq = lane >> 5;

    int bx = blockIdx.x;
    const u16* Bpl = Bp; float* Cl = C; u16* Opl = Op;
    if (bx >= nbx) { bx -= nbx; Bpl = Bp2; Cl = C2; Opl = Op2; }
    const int n0 = bx * BN, m0 = blockIdx.y * BM;
    const long psA = (long)KC * MpA * 8;
    const long psB = (long)KC * N * 8;

    // ---- staging assignment (per-wave instructions, 64 rows x 16B each) ----
    const u16* gb[II]; int gstep[II]; int lo[II]; bool gv[II];
#pragma unroll
    for (int ii = 0; ii < II; ii++) {
        int n = w + 4 * ii;
        gv[ii] = n < NI;
        int nn = gv[ii] ? n : 0;
        int u0 = nn * 64;
        bool isA = u0 < UA;
        int uu = isA ? u0 : u0 - UA;
        int dim = isA ? BM : BN;
        int row0 = uu % dim, pq = uu / dim;
        int q = pq & 1, p = pq >> 1;
        const u16* pb = (isA ? Ap : Bpl) + (long)p * (isA ? psA : psB);
        int mp = isA ? MpA : N;
        gb[ii] = pb + ((long)q * mp + (isA ? m0 : n0) + row0 + lane) * 8;
        gstep[ii] = mp * 16;              // ushorts per tile (2 chunks)
        // LDS dest mirrors the global source: per-lane row offset included.
        lo[ii] = (isA ? (pq * BM + row0) : (6 * BM + pq * BN + row0)) * 8 + lane * 8;
    }

    f32x16 ah[FI][FJ], al[FI][FJ];
#pragma unroll
    for (int fi = 0; fi < FI; fi++)
#pragma unroll
        for (int fj = 0; fj < FJ; fj++)
#pragma unroll
            for (int r = 0; r < 16; r++) { ah[fi][fj][r] = 0.f; al[fi][fj][r] = 0.f; }

    const int T = KC >> 1;
    short8 pf[II];
#pragma unroll
    for (int ii = 0; ii < II; ii++) if (gv[ii]) pf[ii] = *(const short8*)(gb[ii]);
#pragma unroll
    for (int ii = 0; ii < II; ii++) if (gv[ii]) *(short8*)(sm + lo[ii]) = pf[ii];
    __syncthreads();

    for (int t = 0; t < T; t++) {
        const int cb = (t & 1) * BUF, nb2 = ((t + 1) & 1) * BUF;
        const bool more = (t + 1) < T;
        if (more) {
#pragma unroll
            for (int ii = 0; ii < II; ii++)
                if (gv[ii]) pf[ii] = *(const short8*)(gb[ii] + (long)(t + 1) * gstep[ii]);
        }
        const u16* ab = sm + cb;
        const u16* bb = ab + 6 * BM * 8;
        short8 af[FI][3];
#pragma unroll
        for (int fi = 0; fi < FI; fi++)
#pragma unroll
            for (int p = 0; p < 3; p++)
                af[fi][p] = *(const short8*)(ab + ((p * 2 + lq) * BM + (w >> 1) * WM + fi * 32 + ln31) * 8);
#pragma unroll
        for (int fj = 0; fj < FJ; fj++) {
            const int rB = (w & 1) * WN + fj * 32 + ln31;
            short8 bh = *(const short8*)(bb + ((0 * 2 + lq) * BN + rB) * 8);
            short8 bm_ = *(const short8*)(bb + ((1 * 2 + lq) * BN + rB) * 8);
            short8 bl = *(const short8*)(bb + ((2 * 2 + lq) * BN + rB) * 8);
#pragma unroll
            for (int fi = 0; fi < FI; fi++) {
                ah[fi][fj] = __builtin_amdgcn_mfma_f32_32x32x16_bf16(af[fi][0], bh,  ah[fi][fj], 0, 0, 0);
                al[fi][fj] = __builtin_amdgcn_mfma_f32_32x32x16_bf16(af[fi][0], bm_, al[fi][fj], 0, 0, 0);
                al[fi][fj] = __builtin_amdgcn_mfma_f32_32x32x16_bf16(af[fi][1], bh,  al[fi][fj], 0, 0, 0);
                al[fi][fj] = __builtin_amdgcn_mfma_f32_32x32x16_bf16(af[fi][0], bl,  al[fi][fj], 0, 0, 0);
                al[fi][fj] = __builtin_amdgcn_mfma_f32_32x32x16_bf16(af[fi][1], bm_, al[fi][fj], 0, 0, 0);
                al[fi][fj] = __builtin_amdgcn_mfma_f32_32x32x16_bf16(af[fi][2], bh,  al[fi][fj], 0, 0, 0);
            }
        }
        if (more) {
#pragma unroll
            for (int ii = 0; ii < II; ii++)
                if (gv[ii]) *(short8*)(sm + nb2 + lo[ii]) = pf[ii];
        }
        __syncthreads();
    }

    // ---- epilogue ----
    float* bounce = (float*)sm + w * 1184;     // 32x36 floats, per-wave region
    const long psO = (long)N * MpO;            // ushorts per out plane
#pragma unroll
    for (int fi = 0; fi < FI; fi++) {
#pragma unroll
        for (int fj = 0; fj < FJ; fj++) {
            const int colBase = n0 + (w & 1) * WN + fj * 32;
            const int rowBase = m0 + (w >> 1) * WM + fi * 32;
            float bv = bias ? bias[colBase + ln31] : 0.f;
            float v[16];
#pragma unroll
            for (int r = 0; r < 16; r++) {
                float x = ah[fi][fj][r] + (al[fi][fj][r] + bv);
                if (doRelu) x = fmaxf(x, 0.f);
                v[r] = x;
            }
            if (Cl) {
#pragma unroll
                for (int r = 0; r < 16; r++) {
                    int row = rowBase + (r & 3) + 8 * (r >> 2) + 4 * lq;
                    if (row < M)
                        Cl[(long)row * ldc + colBase + ln31] = v[r];
                }
            }
            if (Opl) {
#pragma unroll
                for (int r = 0; r < 16; r++)
                    bounce[((r & 3) + 8 * (r >> 2) + 4 * lq) * 36 + ln31] = v[r];
#pragma unroll
                for (int u = 0; u < 2; u++) {
                    int urow = ln31, uc = lq + 2 * u;
                    const float* rp = bounce + urow * 36 + uc * 8;
                    short8 h8, m8, l8;
#pragma unroll
                    for (int j = 0; j < 8; j++) {
                        short a, b, c2; split3(rp[j], a, b, c2);
                        h8[j] = a; m8[j] = b; l8[j] = c2;
                    }
                    long cIdx = (long)((colBase + uc * 8) >> 3);
                    long base = (cIdx * MpO + rowBase + urow) * 8;
                    *(short8*)(Opl + base) = h8;
                    *(short8*)(Opl + psO + base) = m8;
                    *(short8*)(Opl + 2 * psO + base) = l8;
                }
            }
        }
    }
}

// ---- split weights: W [K][N] fp32 -> 3 planes [K/8][N][8] bf16 ----
__global__ __launch_bounds__(256) void split_b(
    const float* __restrict__ W, int K, int N, int KC,
    u16* __restrict__ Op)
{
    __shared__ float tl[64][65];
    const int tid = threadIdx.x;
    const int n0 = blockIdx.x * 64, k0 = blockIdx.y * 64;
    const long ps = (long)KC * N * 8;
#pragma unroll
    for (int l = 0; l < 4; l++) {
        int k = (tid >> 4) + l * 16;
        int nn = (tid & 15) << 2;
        float4 v = make_float4(0.f, 0.f, 0.f, 0.f);
        if (k0 + k < K) v = ld4(W + (long)(k0 + k) * N + n0 + nn);
        tl[k][nn] = v.x; tl[k][nn + 1] = v.y; tl[k][nn + 2] = v.z; tl[k][nn + 3] = v.w;
    }
    __syncthreads();
#pragma unroll
    for (int l = 0; l < 2; l++) {
        int u = tid + l * 256;
        int n = u & 63, c = u >> 6;
        short8 h8, m8, l8;
#pragma unroll
        for (int j = 0; j < 8; j++) {
            short a, b, c2; split3(tl[c * 8 + j][n], a, b, c2);
            h8[j] = a; m8[j] = b; l8[j] = c2;
        }
        long base = ((long)(k0 / 8 + c) * N + n0 + n) * 8;
        *(short8*)(Op + base) = h8;
        *(short8*)(Op + ps + base) = m8;
        *(short8*)(Op + 2 * ps + base) = l8;
    }
}

__device__ __forceinline__ void store_planes(u16* Op, long ps, long base, const float* x)
{
    short8 h8, m8, l8;
#pragma unroll
    for (int j = 0; j < 8; j++) {
        short a, b, c2; split3(x[j], a, b, c2);
        h8[j] = a; m8[j] = b; l8[j] = c2;
    }
    *(short8*)(Op + base) = h8;
    *(short8*)(Op + ps + base) = m8;
    *(short8*)(Op + 2 * ps + base) = l8;
}

// ---- concat(A | Tab[idx]) fp32 -> planes [KC][Mp][8] ----
__global__ __launch_bounds__(256) void split_concat_a(
    const float* __restrict__ E, int ldE, int KA,
    const float* __restrict__ Tab, int DWc,
    const int* __restrict__ idx, int idxStride,
    int mBase, int Mvalid, int Mp, int KC,
    u16* __restrict__ Op)
{
    int m = blockIdx.x * 256 + threadIdx.x;
    if (m >= Mp) return;
    int c = blockIdx.y;
    int gm = mBase + m;
    float x[8];
    if (gm >= Mvalid) {
#pragma unroll
        for (int j = 0; j < 8; j++) x[j] = 0.f;
    } else {
        int k0 = c * 8;
        if (k0 + 8 <= KA) {
            float4 a = ld4(E + (long)gm * ldE + k0);
            float4 b = ld4(E + (long)gm * ldE + k0 + 4);
            x[0] = a.x; x[1] = a.y; x[2] = a.z; x[3] = a.w;
            x[4] = b.x; x[5] = b.y; x[6] = b.z; x[7] = b.w;
        } else {
            const float* tr = Tab + (long)idx[(long)gm * idxStride] * DWc;
#pragma unroll
            for (int j = 0; j < 8; j++) {
                int k = k0 + j;
                x[j] = (k < KA) ? E[(long)gm * ldE + k]
                                : ((k - KA) < DWc ? tr[k - KA] : 0.f);
            }
        }
    }
    store_planes(Op, (long)KC * Mp * 8, ((long)c * Mp + m) * 8, x);
}

// ---- edge combine: relu(P1[s]+PP+P2[o]+b1a) -> planes (KC=64) ----
__global__ __launch_bounds__(256) void edge_planes(
    const float* __restrict__ PPv, const float* __restrict__ P1v,
    const float* __restrict__ P2v, const int* __restrict__ rels,
    const float* __restrict__ b1a, int Mp, u16* __restrict__ Op)
{
    int m = blockIdx.x * 256 + threadIdx.x;
    if (m >= Mp) return;
    int c = blockIdx.y;
    float x[8];
    if (m >= T_N) {
#pragma unroll
        for (int j = 0; j < 8; j++) x[j] = 0.f;
    } else {
        int s = rels[3 * m], o = rels[3 * m + 2];
        const float* pp = PPv + (long)m * HH_ + c * 8;
        const float* p1 = P1v + (long)s * HH_ + c * 8;
        const float* p2 = P2v + (long)o * HH_ + c * 8;
        const float* bb = b1a + c * 8;
#pragma unroll
        for (int j = 0; j < 8; j++)
            x[j] = fmaxf(pp[j] + p1[j] + p2[j] + bb[j], 0.f);
    }
    store_planes(Op, (long)64 * Mp * 8, ((long)c * Mp + m) * 8, x);
}

// ---- pooled/cnt -> planes (KC=64) ----
__global__ __launch_bounds__(256) void pool_planes(
    const float* __restrict__ PO, const int* __restrict__ CNT,
    int Mp, u16* __restrict__ Op)
{
    int m = blockIdx.x * 256 + threadIdx.x;
    if (m >= Mp) return;
    int c = blockIdx.y;
    float x[8];
    if (m >= O_N) {
#pragma unroll
        for (int j = 0; j < 8; j++) x[j] = 0.f;
    } else {
        int cc = CNT[m]; float cf = 1.f / (float)(cc < 1 ? 1 : cc);
#pragma unroll
        for (int j = 0; j < 8; j++) x[j] = PO[(long)m * HH_ + c * 8 + j] * cf;
    }
    store_planes(Op, (long)64 * Mp * 8, ((long)c * Mp + m) * 8, x);
}

// ---- T2 mid slice -> PV planes (KC=64) ----
__global__ __launch_bounds__(256) void predcopy_planes(
    const float* __restrict__ T2, int Mp, u16* __restrict__ Op)
{
    int m = blockIdx.x * 256 + threadIdx.x;
    if (m >= Mp) return;
    int c = blockIdx.y;
    float x[8];
    if (m >= T_N) {
#pragma unroll
        for (int j = 0; j < 8; j++) x[j] = 0.f;
    } else {
#pragma unroll
        for (int j = 0; j < 8; j++) x[j] = T2[(long)m * 1536 + 512 + c * 8 + j];
    }
    store_planes(Op, (long)64 * Mp * 8, ((long)c * Mp + m) * 8, x);
}

__global__ void predcopy_f32(const float* __restrict__ T2, float* __restrict__ dst)
{
    int i = blockIdx.x * 256 + threadIdx.x;   // float4 index
    if (i >= T_N * HH_ / 4) return;
    int e = i / (HH_ / 4);
    int j = (i % (HH_ / 4)) << 2;
    float4 v = ld4(T2 + (long)e * 1536 + 512 + j);
    *(float4*)(dst + (long)e * HH_ + j) = v;
}

__global__ void count_edges(const int* __restrict__ rels, int* __restrict__ CNT)
{
    int e = blockIdx.x * 256 + threadIdx.x;
    if (e >= T_N) return;
    atomicAdd(CNT + rels[3 * e + 0], 1);
    atomicAdd(CNT + rels[3 * e + 2], 1);
}

__global__ void scatter_pool(const float* __restrict__ T2,
                             const int* __restrict__ rels,
                             float* __restrict__ PO)
{
    int e = blockIdx.x;
    int t = threadIdx.x;            // 256
    int s = rels[e * 3 + 0];
    int o = rels[e * 3 + 2];
#pragma unroll
    for (int u = 0; u < 2; u++) {
        int j = t + u * 256;
        unsafeAtomicAdd(PO + (long)s * HH_ + j, T2[(long)e * 1536 + j]);
        unsafeAtomicAdd(PO + (long)o * HH_ + j, T2[(long)e * 1536 + 1024 + j]);
    }
}

// ---- host-side helpers ----
template<int BM, int BN>
static inline void GX(hipStream_t st, const u16* Ap, int MpA,
                      const u16* Bp, int N, int KC, int M,
                      const float* bias, int relu_,
                      float* C, int ldc, u16* Op, int MpO,
                      const u16* Bp2, float* C2, u16* Op2)
{
    int nbx = N / BN;
    int pair = (Bp2 != nullptr) ? 2 : 1;
    dim3 g(nbx * pair, MpA / BM), b(256);
    gemm_mx<BM, BN><<<g, b, 0, st>>>(Ap, MpA, Bp, N, KC, M, bias, relu_,
                                     C, ldc, Op, MpO, Bp2, C2, Op2, nbx);
}

static inline void SB(hipStream_t st, const float* W, int K, int N, int KC, u16* Op)
{
    dim3 g(N / 64, KC / 8), b(256);
    split_b<<<g, b, 0, st>>>(W, K, N, KC, Op);
}

extern "C" void kernel_launch(void* const* d_in, const int* in_sizes, int n_in,
                              void* d_out, int out_size, void* d_ws, size_t ws_size,
                              hipStream_t stream)
{
    const float* obj_embs  = (const float*)d_in[0];
    const float* pred_embs = (const float*)d_in[2];
    const int*   rels      = (const int*)d_in[4];
    const int*   objs      = (const int*)d_in[5];
    const float* obj_table = (const float*)d_in[6];
    const float* rel_table = (const float*)d_in[7];
    const float* Wf_obj = (const float*)d_in[8];
    const float* bf_obj = (const float*)d_in[9];
    const float* Wf_rel = (const float*)d_in[10];
    const float* bf_rel = (const float*)d_in[11];
    const float* W1a = (const float*)d_in[12];
    const float* b1a = (const float*)d_in[13];
    const float* W1b = (const float*)d_in[14];
    const float* b1b = (const float*)d_in[15];
    const float* W2a = (const float*)d_in[16];
    const float* b2a = (const float*)d_in[17];
    const float* W2b = (const float*)d_in[18];
    const float* b2b = (const float*)d_in[19];
    const float* Ws1a = (const float*)d_in[20];
    const float* bs1a = (const float*)d_in[21];
    const float* Ws1b = (const float*)d_in[22];
    const float* bs1b = (const float*)d_in[23];
    const float* Ws2a = (const float*)d_in[24];
    const float* bs2a = (const float*)d_in[25];
    const float* Ws2b = (const float*)d_in[26];
    const float* bs2b = (const float*)d_in[27];
    float* out = (float*)d_out;

    // ---- workspace layout (bytes), total ~119.6 MB ----
    unsigned char* B8 = (unsigned char*)d_ws;
    constexpr size_t S1O  = 0;                     // concat-A planes    29,097,984
    constexpr size_t S2O  = 29097984;              // chunk-out planes   25,165,824
    constexpr size_t S3AO = 54263808;              // Wf B planes        29,097,984
    constexpr size_t ZSZ  = 86507520;              // overlay-zone size
    //   overlays inside zone (live only after L0's PP GEMM):
    constexpr size_t T2O  = 0;                     // 36,864,000
    constexpr size_t TTO  = 36864000;              // 18,481,152 (TTp / Hp)
    constexpr size_t PVO  = 55345152;              // 18,481,152 (PVpS)
    constexpr size_t PLO  = 73826304;              //  6,291,456 (PLp)
    constexpr size_t OVO  = 80117760;              //  6,291,456 (OVpS)
    constexpr size_t S3BO = ZSZ;                   //  6,291,456 (B slot b)
    constexpr size_t S3CO = S3BO + 6291456;        //  6,291,456 (B slot c)
    constexpr size_t PPO  = S3CO + 6291456;        // 12,288,000
    constexpr size_t P1O  = PPO + 12288000;        //  4,096,000 (also PO)
    constexpr size_t P2O  = P1O + 4096000;         //  4,096,000
    constexpr size_t CNO  = P2O + 4096000;         //  8,000

    u16* S1  = (u16*)(B8 + S1O);
    u16* S2  = (u16*)(B8 + S2O);
    u16* S3A = (u16*)(B8 + S3AO);
    u16* S3B = (u16*)(B8 + S3BO);
    u16* S3C = (u16*)(B8 + S3CO);
    float* T2 = (float*)(B8 + T2O);
    u16* TTp  = (u16*)(B8 + TTO);
    u16* Hp   = (u16*)(B8 + TTO);                 // overlays TTp (disjoint in time)
    u16* PVp  = (u16*)(B8 + PVO);
    u16* PLp  = (u16*)(B8 + PLO);
    u16* OVp  = (u16*)(B8 + OVO);
    float* PP = (float*)(B8 + PPO);
    float* P1 = (float*)(B8 + P1O);
    float* P2 = (float*)(B8 + P2O);
    float* PO = P1;                                // reuse (P1 dead after edge)
    int* CNT  = (int*)(B8 + CNO);

    // ---- edge counts (fixed for whole call) ----
    hipMemsetAsync(CNT, 0, O_N * sizeof(int), stream);
    hipLaunchKernelGGL(count_edges, dim3((T_N + 255) / 256), dim3(256), 0, stream, rels, CNT);

    // ================= projections + layer-0 front =================
    // obj: OV-chunk planes -> P1/P2 via W1a top/bot
    SB(stream, Wf_obj, DIN + DW, DIN, 296, S3A);
    {
        dim3 g(8, 296), b(256);
        split_concat_a<<<g, b, 0, stream>>>(obj_embs, DIN, DIN, obj_table, DW,
                                            objs, 1, 0, O_N, 2048, 296, S1);
    }
    // BN=64: 512 blocks -> 2 blocks/CU (was 256 blocks = 1/CU, latency-exposed)
    GX<128, 64>(stream, S1, 2048, S3A, DIN, 296, O_N, bf_obj, 1,
                nullptr, 0, S2, 2048, nullptr, nullptr, nullptr);
    SB(stream, W1a, DIN, HH_, 256, S3B);                       // top (L0 K=2048)
    SB(stream, W1a + (size_t)2 * DIN * HH_, DIN, HH_, 256, S3C); // bot
    GX<128, 64>(stream, S2, 2048, S3B, HH_, 256, O_N, nullptr, 0,
                P1, HH_, nullptr, 0, S3C, P2, nullptr);
    // pred, M-chunked: proj -> PV-chunk planes -> PP via W1a mid
    SB(stream, Wf_rel, DIN + DW, DIN, 296, S3A);
    SB(stream, W1a + (size_t)DIN * HH_, DIN, HH_, 256, S3B);   // mid
    for (int ch = 0; ch < 3; ch++) {
        int ch0 = ch * 2048;
        int mp  = (ch == 2) ? 1920 : 2048;
        int mv  = (ch == 2) ? 1904 : 2048;
        dim3 g((mp + 255) / 256, 296), b(256);
        split_concat_a<<<g, b, 0, stream>>>(pred_embs, DIN, DIN, rel_table, DW,
                                            rels + 1, 3, ch0, T_N, mp, 296, S1);
        // BN=64: 2x grid for the K=2368 front GEMM
        GX<128, 64>(stream, S1, mp, S3A, DIN, 296, mv, bf_rel, 1,
                    nullptr, 0, S2, mp, nullptr, nullptr, nullptr);
        GX<128, 64>(stream, S2, mp, S3B, HH_, 256, mv, nullptr, 0,
                    PP + (size_t)ch0 * HH_, HH_, nullptr, 0,
                    nullptr, nullptr, nullptr);
    }

    // ================= 5 conv layers =================
    for (int L = 0; L < 5; L++) {
        const float* bb1a = (L == 0) ? b1a : (bs1a + (size_t)(L - 1) * HH_);
        const float* w1b  = (L == 0) ? W1b : (Ws1b + (size_t)(L - 1) * HH_ * 1536);
        const float* bb1b = (L == 0) ? b1b : (bs1b + (size_t)(L - 1) * 1536);
        const float* w2a  = (L == 0) ? W2a : (Ws2a + (size_t)(L - 1) * HH_ * HH_);
        const float* bb2a = (L == 0) ? b2a : (bs2a + (size_t)(L - 1) * HH_);
        const float* w2b  = (L == 0) ? W2b : (Ws2b + (size_t)(L - 1) * HH_ * DG);
        const float* bb2b = (L == 0) ? b2b : (bs2b + (size_t)(L - 1) * DG);

        if (L > 0) {
            const float* w1a = Ws1a + (size_t)(L - 1) * 3 * HH_ * HH_;
            SB(stream, w1a, HH_, HH_, 64, S3B);                       // top
            SB(stream, w1a + (size_t)2 * HH_ * HH_, HH_, HH_, 64, S3C); // bot
            GX<128, 64>(stream, OVp, 2048, S3B, HH_, 64, O_N, nullptr, 0,
                        P1, HH_, nullptr, 0, S3C, P2, nullptr);
            SB(stream, w1a + (size_t)HH_ * HH_, HH_, HH_, 64, S3B);   // mid
            GX<128, 64>(stream, PVp, 6016, S3B, HH_, 64, T_N, nullptr, 0,
                        PP, HH_, nullptr, 0, nullptr, nullptr, nullptr);
        }

        // edge combine -> TT planes
        {
            dim3 g(24, 64), b(256);
            edge_planes<<<g, b, 0, stream>>>(PP, P1, P2, rels, bb1a, 6016, TTp);
        }
        // t2 = relu(TT @ W1b + b1b)  — BN=64: 1128 blocks (was 564)
        SB(stream, w1b, HH_, 1536, 64, S3C);
        GX<128, 64>(stream, TTp, 6016, S3C, 1536, 64, T_N, bb1b, 1,
                    T2, 1536, nullptr, 0, nullptr, nullptr, nullptr);
        // pooling
        hipMemsetAsync(PO, 0, (size_t)O_N * HH_ * sizeof(float), stream);
        hipLaunchKernelGGL(scatter_pool, dim3(T_N), dim3(256), 0, stream, T2, rels, PO);
        {
            dim3 g(8, 64), b(256);
            pool_planes<<<g, b, 0, stream>>>(PO, CNT, 2048, PLp);
        }
        // obj MLP2
        SB(stream, w2a, HH_, HH_, 64, S3B);
        GX<128, 64>(stream, PLp, 2048, S3B, HH_, 64, O_N, bb2a, 1,
                    nullptr, 0, Hp, 2048, nullptr, nullptr, nullptr);
        SB(stream, w2b, HH_, DG, 64, S3C);
        if (L < 4) {
            GX<128, 64>(stream, Hp, 2048, S3C, DG, 64, O_N, bb2b, 1,
                        nullptr, 0, OVp, 2048, nullptr, nullptr, nullptr);
            dim3 g(24, 64), b(256);
            predcopy_planes<<<g, b, 0, stream>>>(T2, 6016, PVp);
        } else {
            GX<128, 64>(stream, Hp, 2048, S3C, DG, 64, O_N, bb2b, 1,
                        out, DG, nullptr, 0, nullptr, nullptr, nullptr);
            hipLaunchKernelGGL(predcopy_f32, dim3((T_N * HH_ / 4 + 255) / 256),
                               dim3(256), 0, stream, T2, out + (size_t)O_N * DG);
        }
    }
}

// Round 2
// 2150.827 us; speedup vs baseline: 1.3111x; 1.0231x over previous
//
#include <hip/hip_runtime.h>

#define O_N 2000
#define T_N 6000
#define DIN 2048
#define DW  300
#define DG  512
#define HH_ 512

typedef __attribute__((ext_vector_type(8)))  short short8;
typedef __attribute__((ext_vector_type(16))) float f32x16;
typedef unsigned short u16;

__device__ __forceinline__ float4 ld4(const float* p) { return *(const float4*)p; }

// ---- bf16 split-3 helpers (RNE) ----
__device__ __forceinline__ u16 rbf(float x) {
    unsigned int u = __float_as_uint(x);
    u += 0x7FFFu + ((u >> 16) & 1u);
    return (u16)(u >> 16);
}
__device__ __forceinline__ float fbf(u16 h) {
    return __uint_as_float((unsigned int)h << 16);
}
__device__ __forceinline__ void split3(float x, short& h, short& m, short& l) {
    u16 a = rbf(x);
    float r = x - fbf(a);
    u16 b = rbf(r);
    r -= fbf(b);
    u16 c = rbf(r);
    h = (short)a; m = (short)b; l = (short)c;
}

// =====================================================================
// MFMA GEMM: C = act(A @ B + bias) with A,B given as 3 bf16 planes
// (hi/mid/lo), chunk-major layout [K/8][Mp][8] (A) / [K/8][N][8] (B).
// 6 MFMA products: hh -> acc_hi ; hm, mh, hl, mm, lh -> acc_lo.
// Block 256 = 4 waves (2x2), wave tile (BM/2) x (BN/2), 32x32x16 MFMA.
// Double-buffered LDS, one barrier per K=16 tile.
// BM=128: 36.9 KB LDS, 2 blocks/CU min.  BM=64: 24 KB LDS, 4 blocks/CU
// min — used for grid-starved shapes (grid would be <= 2 blocks/CU at
// BM=128; occupancy there is grid-limited, not resource-limited).
// Optional fp32 C out and/or bf16-plane out (for the next GEMM's A).
// Pair mode: gridDim.x doubled; bx >= nbx uses Bp2/C2/Op2.
// =====================================================================
template<int BM, int BN>
__global__ __launch_bounds__(256, (BM == 64 ? 4 : 2)) void gemm_mx(
    const u16* __restrict__ Ap, int MpA,
    const u16* __restrict__ Bp, int N, int KC, int M,
    const float* __restrict__ bias, int doRelu,
    float* __restrict__ C, int ldc,
    u16* __restrict__ Op, int MpO,
    const u16* __restrict__ Bp2, float* __restrict__ C2, u16* __restrict__ Op2,
    int nbx)
{
    static_assert(BM == 128 || BM == 64, "BM in {64,128}");
    constexpr int WM = BM / 2, WN = BN / 2;
    constexpr int FI = WM / 32, FJ = WN / 32;
    constexpr int UA = 6 * BM;            // 16B staging units per tile (A)
    constexpr int UB = 6 * BN;
    constexpr int NI = (UA + UB) / 64;    // staging instructions per tile
    constexpr int II = (NI + 3) / 4;      // per wave
    constexpr int BUF = (BM + BN) * 48;   // ushorts per LDS buffer
    __shared__ u16 sm[2 * BUF];

    const int tid = threadIdx.x;
    const int w = tid >> 6, lane = tid & 63;
    const int ln31 = lane & 31, lq = lane >> 5;

    int bx = blockIdx.x;
    const u16* Bpl = Bp; float* Cl = C; u16* Opl = Op;
    if (bx >= nbx) { bx -= nbx; Bpl = Bp2; Cl = C2; Opl = Op2; }
    const int n0 = bx * BN, m0 = blockIdx.y * BM;
    const long psA = (long)KC * MpA * 8;
    const long psB = (long)KC * N * 8;

    // ---- staging assignment (per-wave instructions, 64 rows x 16B each) ----
    const u16* gb[II]; int gstep[II]; int lo[II]; bool gv[II];
#pragma unroll
    for (int ii = 0; ii < II; ii++) {
        int n = w + 4 * ii;
        gv[ii] = n < NI;
        int nn = gv[ii] ? n : 0;
        int u0 = nn * 64;
        bool isA = u0 < UA;
        int uu = isA ? u0 : u0 - UA;
        int dim = isA ? BM : BN;
        int row0 = uu % dim, pq = uu / dim;
        int q = pq & 1, p = pq >> 1;
        const u16* pb = (isA ? Ap : Bpl) + (long)p * (isA ? psA : psB);
        int mp = isA ? MpA : N;
        gb[ii] = pb + ((long)q * mp + (isA ? m0 : n0) + row0 + lane) * 8;
        gstep[ii] = mp * 16;              // ushorts per tile (2 chunks)
        // LDS dest mirrors the global source: per-lane row offset included.
        lo[ii] = (isA ? (pq * BM + row0) : (6 * BM + pq * BN + row0)) * 8 + lane * 8;
    }

    f32x16 ah[FI][FJ], al[FI][FJ];
#pragma unroll
    for (int fi = 0; fi < FI; fi++)
#pragma unroll
        for (int fj = 0; fj < FJ; fj++)
#pragma unroll
            for (int r = 0; r < 16; r++) { ah[fi][fj][r] = 0.f; al[fi][fj][r] = 0.f; }

    const int T = KC >> 1;
    short8 pf[II];
#pragma unroll
    for (int ii = 0; ii < II; ii++) if (gv[ii]) pf[ii] = *(const short8*)(gb[ii]);
#pragma unroll
    for (int ii = 0; ii < II; ii++) if (gv[ii]) *(short8*)(sm + lo[ii]) = pf[ii];
    __syncthreads();

    for (int t = 0; t < T; t++) {
        const int cb = (t & 1) * BUF, nb2 = ((t + 1) & 1) * BUF;
        const bool more = (t + 1) < T;
        if (more) {
#pragma unroll
            for (int ii = 0; ii < II; ii++)
                if (gv[ii]) pf[ii] = *(const short8*)(gb[ii] + (long)(t + 1) * gstep[ii]);
        }
        const u16* ab = sm + cb;
        const u16* bb = ab + 6 * BM * 8;
        short8 af[FI][3];
#pragma unroll
        for (int fi = 0; fi < FI; fi++)
#pragma unroll
            for (int p = 0; p < 3; p++)
                af[fi][p] = *(const short8*)(ab + ((p * 2 + lq) * BM + (w >> 1) * WM + fi * 32 + ln31) * 8);
#pragma unroll
        for (int fj = 0; fj < FJ; fj++) {
            const int rB = (w & 1) * WN + fj * 32 + ln31;
            short8 bh = *(const short8*)(bb + ((0 * 2 + lq) * BN + rB) * 8);
            short8 bm_ = *(const short8*)(bb + ((1 * 2 + lq) * BN + rB) * 8);
            short8 bl = *(const short8*)(bb + ((2 * 2 + lq) * BN + rB) * 8);
#pragma unroll
            for (int fi = 0; fi < FI; fi++) {
                ah[fi][fj] = __builtin_amdgcn_mfma_f32_32x32x16_bf16(af[fi][0], bh,  ah[fi][fj], 0, 0, 0);
                al[fi][fj] = __builtin_amdgcn_mfma_f32_32x32x16_bf16(af[fi][0], bm_, al[fi][fj], 0, 0, 0);
                al[fi][fj] = __builtin_amdgcn_mfma_f32_32x32x16_bf16(af[fi][1], bh,  al[fi][fj], 0, 0, 0);
                al[fi][fj] = __builtin_amdgcn_mfma_f32_32x32x16_bf16(af[fi][0], bl,  al[fi][fj], 0, 0, 0);
                al[fi][fj] = __builtin_amdgcn_mfma_f32_32x32x16_bf16(af[fi][1], bm_, al[fi][fj], 0, 0, 0);
                al[fi][fj] = __builtin_amdgcn_mfma_f32_32x32x16_bf16(af[fi][2], bh,  al[fi][fj], 0, 0, 0);
            }
        }
        if (more) {
#pragma unroll
            for (int ii = 0; ii < II; ii++)
                if (gv[ii]) *(short8*)(sm + nb2 + lo[ii]) = pf[ii];
        }
        __syncthreads();
    }

    // ---- epilogue ----
    float* bounce = (float*)sm + w * 1184;     // 32x36 floats, per-wave region
    const long psO = (long)N * MpO;            // ushorts per out plane
#pragma unroll
    for (int fi = 0; fi < FI; fi++) {
#pragma unroll
        for (int fj = 0; fj < FJ; fj++) {
            const int colBase = n0 + (w & 1) * WN + fj * 32;
            const int rowBase = m0 + (w >> 1) * WM + fi * 32;
            float bv = bias ? bias[colBase + ln31] : 0.f;
            float v[16];
#pragma unroll
            for (int r = 0; r < 16; r++) {
                float x = ah[fi][fj][r] + (al[fi][fj][r] + bv);
                if (doRelu) x = fmaxf(x, 0.f);
                v[r] = x;
            }
            if (Cl) {
#pragma unroll
                for (int r = 0; r < 16; r++) {
                    int row = rowBase + (r & 3) + 8 * (r >> 2) + 4 * lq;
                    if (row < M)
                        Cl[(long)row * ldc + colBase + ln31] = v[r];
                }
            }
            if (Opl) {
#pragma unroll
                for (int r = 0; r < 16; r++)
                    bounce[((r & 3) + 8 * (r >> 2) + 4 * lq) * 36 + ln31] = v[r];
#pragma unroll
                for (int u = 0; u < 2; u++) {
                    int urow = ln31, uc = lq + 2 * u;
                    const float* rp = bounce + urow * 36 + uc * 8;
                    short8 h8, m8, l8;
#pragma unroll
                    for (int j = 0; j < 8; j++) {
                        short a, b, c2; split3(rp[j], a, b, c2);
                        h8[j] = a; m8[j] = b; l8[j] = c2;
                    }
                    long cIdx = (long)((colBase + uc * 8) >> 3);
                    long base = (cIdx * MpO + rowBase + urow) * 8;
                    *(short8*)(Opl + base) = h8;
                    *(short8*)(Opl + psO + base) = m8;
                    *(short8*)(Opl + 2 * psO + base) = l8;
                }
            }
        }
    }
}

// ---- split weights: W [K][N] fp32 -> 3 planes [K/8][N][8] bf16 ----
__global__ __launch_bounds__(256) void split_b(
    const float* __restrict__ W, int K, int N, int KC,
    u16* __restrict__ Op)
{
    __shared__ float tl[64][65];
    const int tid = threadIdx.x;
    const int n0 = blockIdx.x * 64, k0 = blockIdx.y * 64;
    const long ps = (long)KC * N * 8;
#pragma unroll
    for (int l = 0; l < 4; l++) {
        int k = (tid >> 4) + l * 16;
        int nn = (tid & 15) << 2;
        float4 v = make_float4(0.f, 0.f, 0.f, 0.f);
        if (k0 + k < K) v = ld4(W + (long)(k0 + k) * N + n0 + nn);
        tl[k][nn] = v.x; tl[k][nn + 1] = v.y; tl[k][nn + 2] = v.z; tl[k][nn + 3] = v.w;
    }
    __syncthreads();
#pragma unroll
    for (int l = 0; l < 2; l++) {
        int u = tid + l * 256;
        int n = u & 63, c = u >> 6;
        short8 h8, m8, l8;
#pragma unroll
        for (int j = 0; j < 8; j++) {
            short a, b, c2; split3(tl[c * 8 + j][n], a, b, c2);
            h8[j] = a; m8[j] = b; l8[j] = c2;
        }
        long base = ((long)(k0 / 8 + c) * N + n0 + n) * 8;
        *(short8*)(Op + base) = h8;
        *(short8*)(Op + ps + base) = m8;
        *(short8*)(Op + 2 * ps + base) = l8;
    }
}

__device__ __forceinline__ void store_planes(u16* Op, long ps, long base, const float* x)
{
    short8 h8, m8, l8;
#pragma unroll
    for (int j = 0; j < 8; j++) {
        short a, b, c2; split3(x[j], a, b, c2);
        h8[j] = a; m8[j] = b; l8[j] = c2;
    }
    *(short8*)(Op + base) = h8;
    *(short8*)(Op + ps + base) = m8;
    *(short8*)(Op + 2 * ps + base) = l8;
}

// ---- concat(A | Tab[idx]) fp32 -> planes [KC][Mp][8] ----
__global__ __launch_bounds__(256) void split_concat_a(
    const float* __restrict__ E, int ldE, int KA,
    const float* __restrict__ Tab, int DWc,
    const int* __restrict__ idx, int idxStride,
    int mBase, int Mvalid, int Mp, int KC,
    u16* __restrict__ Op)
{
    int m = blockIdx.x * 256 + threadIdx.x;
    if (m >= Mp) return;
    int c = blockIdx.y;
    int gm = mBase + m;
    float x[8];
    if (gm >= Mvalid) {
#pragma unroll
        for (int j = 0; j < 8; j++) x[j] = 0.f;
    } else {
        int k0 = c * 8;
        if (k0 + 8 <= KA) {
            float4 a = ld4(E + (long)gm * ldE + k0);
            float4 b = ld4(E + (long)gm * ldE + k0 + 4);
            x[0] = a.x; x[1] = a.y; x[2] = a.z; x[3] = a.w;
            x[4] = b.x; x[5] = b.y; x[6] = b.z; x[7] = b.w;
        } else {
            const float* tr = Tab + (long)idx[(long)gm * idxStride] * DWc;
#pragma unroll
            for (int j = 0; j < 8; j++) {
                int k = k0 + j;
                x[j] = (k < KA) ? E[(long)gm * ldE + k]
                                : ((k - KA) < DWc ? tr[k - KA] : 0.f);
            }
        }
    }
    store_planes(Op, (long)KC * Mp * 8, ((long)c * Mp + m) * 8, x);
}

// ---- edge combine: relu(P1[s]+PP+P2[o]+b1a) -> planes (KC=64) ----
__global__ __launch_bounds__(256) void edge_planes(
    const float* __restrict__ PPv, const float* __restrict__ P1v,
    const float* __restrict__ P2v, const int* __restrict__ rels,
    const float* __restrict__ b1a, int Mp, u16* __restrict__ Op)
{
    int m = blockIdx.x * 256 + threadIdx.x;
    if (m >= Mp) return;
    int c = blockIdx.y;
    float x[8];
    if (m >= T_N) {
#pragma unroll
        for (int j = 0; j < 8; j++) x[j] = 0.f;
    } else {
        int s = rels[3 * m], o = rels[3 * m + 2];
        const float* pp = PPv + (long)m * HH_ + c * 8;
        const float* p1 = P1v + (long)s * HH_ + c * 8;
        const float* p2 = P2v + (long)o * HH_ + c * 8;
        const float* bb = b1a + c * 8;
#pragma unroll
        for (int j = 0; j < 8; j++)
            x[j] = fmaxf(pp[j] + p1[j] + p2[j] + bb[j], 0.f);
    }
    store_planes(Op, (long)64 * Mp * 8, ((long)c * Mp + m) * 8, x);
}

// ---- pooled/cnt -> planes (KC=64) ----
__global__ __launch_bounds__(256) void pool_planes(
    const float* __restrict__ PO, const int* __restrict__ CNT,
    int Mp, u16* __restrict__ Op)
{
    int m = blockIdx.x * 256 + threadIdx.x;
    if (m >= Mp) return;
    int c = blockIdx.y;
    float x[8];
    if (m >= O_N) {
#pragma unroll
        for (int j = 0; j < 8; j++) x[j] = 0.f;
    } else {
        int cc = CNT[m]; float cf = 1.f / (float)(cc < 1 ? 1 : cc);
#pragma unroll
        for (int j = 0; j < 8; j++) x[j] = PO[(long)m * HH_ + c * 8 + j] * cf;
    }
    store_planes(Op, (long)64 * Mp * 8, ((long)c * Mp + m) * 8, x);
}

// ---- T2 mid slice -> PV planes (KC=64) ----
__global__ __launch_bounds__(256) void predcopy_planes(
    const float* __restrict__ T2, int Mp, u16* __restrict__ Op)
{
    int m = blockIdx.x * 256 + threadIdx.x;
    if (m >= Mp) return;
    int c = blockIdx.y;
    float x[8];
    if (m >= T_N) {
#pragma unroll
        for (int j = 0; j < 8; j++) x[j] = 0.f;
    } else {
#pragma unroll
        for (int j = 0; j < 8; j++) x[j] = T2[(long)m * 1536 + 512 + c * 8 + j];
    }
    store_planes(Op, (long)64 * Mp * 8, ((long)c * Mp + m) * 8, x);
}

__global__ void predcopy_f32(const float* __restrict__ T2, float* __restrict__ dst)
{
    int i = blockIdx.x * 256 + threadIdx.x;   // float4 index
    if (i >= T_N * HH_ / 4) return;
    int e = i / (HH_ / 4);
    int j = (i % (HH_ / 4)) << 2;
    float4 v = ld4(T2 + (long)e * 1536 + 512 + j);
    *(float4*)(dst + (long)e * HH_ + j) = v;
}

__global__ void count_edges(const int* __restrict__ rels, int* __restrict__ CNT)
{
    int e = blockIdx.x * 256 + threadIdx.x;
    if (e >= T_N) return;
    atomicAdd(CNT + rels[3 * e + 0], 1);
    atomicAdd(CNT + rels[3 * e + 2], 1);
}

__global__ void scatter_pool(const float* __restrict__ T2,
                             const int* __restrict__ rels,
                             float* __restrict__ PO)
{
    int e = blockIdx.x;
    int t = threadIdx.x;            // 256
    int s = rels[e * 3 + 0];
    int o = rels[e * 3 + 2];
#pragma unroll
    for (int u = 0; u < 2; u++) {
        int j = t + u * 256;
        unsafeAtomicAdd(PO + (long)s * HH_ + j, T2[(long)e * 1536 + j]);
        unsafeAtomicAdd(PO + (long)o * HH_ + j, T2[(long)e * 1536 + 1024 + j]);
    }
}

// ---- host-side helpers ----
template<int BM, int BN>
static inline void GX(hipStream_t st, const u16* Ap, int MpA,
                      const u16* Bp, int N, int KC, int M,
                      const float* bias, int relu_,
                      float* C, int ldc, u16* Op, int MpO,
                      const u16* Bp2, float* C2, u16* Op2)
{
    int nbx = N / BN;
    int pair = (Bp2 != nullptr) ? 2 : 1;
    dim3 g(nbx * pair, MpA / BM), b(256);
    gemm_mx<BM, BN><<<g, b, 0, st>>>(Ap, MpA, Bp, N, KC, M, bias, relu_,
                                     C, ldc, Op, MpO, Bp2, C2, Op2, nbx);
}

static inline void SB(hipStream_t st, const float* W, int K, int N, int KC, u16* Op)
{
    dim3 g(N / 64, KC / 8), b(256);
    split_b<<<g, b, 0, st>>>(W, K, N, KC, Op);
}

extern "C" void kernel_launch(void* const* d_in, const int* in_sizes, int n_in,
                              void* d_out, int out_size, void* d_ws, size_t ws_size,
                              hipStream_t stream)
{
    const float* obj_embs  = (const float*)d_in[0];
    const float* pred_embs = (const float*)d_in[2];
    const int*   rels      = (const int*)d_in[4];
    const int*   objs      = (const int*)d_in[5];
    const float* obj_table = (const float*)d_in[6];
    const float* rel_table = (const float*)d_in[7];
    const float* Wf_obj = (const float*)d_in[8];
    const float* bf_obj = (const float*)d_in[9];
    const float* Wf_rel = (const float*)d_in[10];
    const float* bf_rel = (const float*)d_in[11];
    const float* W1a = (const float*)d_in[12];
    const float* b1a = (const float*)d_in[13];
    const float* W1b = (const float*)d_in[14];
    const float* b1b = (const float*)d_in[15];
    const float* W2a = (const float*)d_in[16];
    const float* b2a = (const float*)d_in[17];
    const float* W2b = (const float*)d_in[18];
    const float* b2b = (const float*)d_in[19];
    const float* Ws1a = (const float*)d_in[20];
    const float* bs1a = (const float*)d_in[21];
    const float* Ws1b = (const float*)d_in[22];
    const float* bs1b = (const float*)d_in[23];
    const float* Ws2a = (const float*)d_in[24];
    const float* bs2a = (const float*)d_in[25];
    const float* Ws2b = (const float*)d_in[26];
    const float* bs2b = (const float*)d_in[27];
    float* out = (float*)d_out;

    // ---- workspace layout (bytes), total ~119.6 MB ----
    unsigned char* B8 = (unsigned char*)d_ws;
    constexpr size_t S1O  = 0;                     // concat-A planes    29,097,984
    constexpr size_t S2O  = 29097984;              // chunk-out planes   25,165,824
    constexpr size_t S3AO = 54263808;              // Wf B planes        29,097,984
    constexpr size_t ZSZ  = 86507520;              // overlay-zone size
    //   overlays inside zone (live only after L0's PP GEMM):
    constexpr size_t T2O  = 0;                     // 36,864,000
    constexpr size_t TTO  = 36864000;              // 18,481,152 (TTp / Hp)
    constexpr size_t PVO  = 55345152;              // 18,481,152 (PVpS)
    constexpr size_t PLO  = 73826304;              //  6,291,456 (PLp)
    constexpr size_t OVO  = 80117760;              //  6,291,456 (OVpS)
    constexpr size_t S3BO = ZSZ;                   //  6,291,456 (B slot b)
    constexpr size_t S3CO = S3BO + 6291456;        //  6,291,456 (B slot c)
    constexpr size_t PPO  = S3CO + 6291456;        // 12,288,000
    constexpr size_t P1O  = PPO + 12288000;        //  4,096,000 (also PO)
    constexpr size_t P2O  = P1O + 4096000;         //  4,096,000
    constexpr size_t CNO  = P2O + 4096000;         //  8,000

    u16* S1  = (u16*)(B8 + S1O);
    u16* S2  = (u16*)(B8 + S2O);
    u16* S3A = (u16*)(B8 + S3AO);
    u16* S3B = (u16*)(B8 + S3BO);
    u16* S3C = (u16*)(B8 + S3CO);
    float* T2 = (float*)(B8 + T2O);
    u16* TTp  = (u16*)(B8 + TTO);
    u16* Hp   = (u16*)(B8 + TTO);                 // overlays TTp (disjoint in time)
    u16* PVp  = (u16*)(B8 + PVO);
    u16* PLp  = (u16*)(B8 + PLO);
    u16* OVp  = (u16*)(B8 + OVO);
    float* PP = (float*)(B8 + PPO);
    float* P1 = (float*)(B8 + P1O);
    float* P2 = (float*)(B8 + P2O);
    float* PO = P1;                                // reuse (P1 dead after edge)
    int* CNT  = (int*)(B8 + CNO);

    // ---- edge counts (fixed for whole call) ----
    hipMemsetAsync(CNT, 0, O_N * sizeof(int), stream);
    hipLaunchKernelGGL(count_edges, dim3((T_N + 255) / 256), dim3(256), 0, stream, rels, CNT);

    // ================= projections + layer-0 front =================
    // obj: OV-chunk planes -> P1/P2 via W1a top/bot
    SB(stream, Wf_obj, DIN + DW, DIN, 296, S3A);
    {
        dim3 g(8, 296), b(256);
        split_concat_a<<<g, b, 0, stream>>>(obj_embs, DIN, DIN, obj_table, DW,
                                            objs, 1, 0, O_N, 2048, 296, S1);
    }
    // BM=64: 1024 blocks -> 4 blocks/CU (was 512 = 2/CU, phase-serialized)
    GX<64, 64>(stream, S1, 2048, S3A, DIN, 296, O_N, bf_obj, 1,
               nullptr, 0, S2, 2048, nullptr, nullptr, nullptr);
    SB(stream, W1a, DIN, HH_, 256, S3B);                       // top (L0 K=2048)
    SB(stream, W1a + (size_t)2 * DIN * HH_, DIN, HH_, 256, S3C); // bot
    GX<64, 64>(stream, S2, 2048, S3B, HH_, 256, O_N, nullptr, 0,
               P1, HH_, nullptr, 0, S3C, P2, nullptr);
    // pred, M-chunked: proj -> PV-chunk planes -> PP via W1a mid
    SB(stream, Wf_rel, DIN + DW, DIN, 296, S3A);
    SB(stream, W1a + (size_t)DIN * HH_, DIN, HH_, 256, S3B);   // mid
    for (int ch = 0; ch < 3; ch++) {
        int ch0 = ch * 2048;
        int mp  = (ch == 2) ? 1920 : 2048;
        int mv  = (ch == 2) ? 1904 : 2048;
        dim3 g((mp + 255) / 256, 296), b(256);
        split_concat_a<<<g, b, 0, stream>>>(pred_embs, DIN, DIN, rel_table, DW,
                                            rels + 1, 3, ch0, T_N, mp, 296, S1);
        GX<64, 64>(stream, S1, mp, S3A, DIN, 296, mv, bf_rel, 1,
                   nullptr, 0, S2, mp, nullptr, nullptr, nullptr);
        GX<64, 64>(stream, S2, mp, S3B, HH_, 256, mv, nullptr, 0,
                   PP + (size_t)ch0 * HH_, HH_, nullptr, 0,
                   nullptr, nullptr, nullptr);
    }

    // ================= 5 conv layers =================
    for (int L = 0; L < 5; L++) {
        const float* bb1a = (L == 0) ? b1a : (bs1a + (size_t)(L - 1) * HH_);
        const float* w1b  = (L == 0) ? W1b : (Ws1b + (size_t)(L - 1) * HH_ * 1536);
        const float* bb1b = (L == 0) ? b1b : (bs1b + (size_t)(L - 1) * 1536);
        const float* w2a  = (L == 0) ? W2a : (Ws2a + (size_t)(L - 1) * HH_ * HH_);
        const float* bb2a = (L == 0) ? b2a : (bs2a + (size_t)(L - 1) * HH_);
        const float* w2b  = (L == 0) ? W2b : (Ws2b + (size_t)(L - 1) * HH_ * DG);
        const float* bb2b = (L == 0) ? b2b : (bs2b + (size_t)(L - 1) * DG);

        if (L > 0) {
            const float* w1a = Ws1a + (size_t)(L - 1) * 3 * HH_ * HH_;
            SB(stream, w1a, HH_, HH_, 64, S3B);                       // top
            SB(stream, w1a + (size_t)2 * HH_ * HH_, HH_, HH_, 64, S3C); // bot
            GX<64, 64>(stream, OVp, 2048, S3B, HH_, 64, O_N, nullptr, 0,
                       P1, HH_, nullptr, 0, S3C, P2, nullptr);
            SB(stream, w1a + (size_t)HH_ * HH_, HH_, HH_, 64, S3B);   // mid
            GX<64, 64>(stream, PVp, 6016, S3B, HH_, 64, T_N, nullptr, 0,
                       PP, HH_, nullptr, 0, nullptr, nullptr, nullptr);
        }

        // edge combine -> TT planes
        {
            dim3 g(24, 64), b(256);
            edge_planes<<<g, b, 0, stream>>>(PP, P1, P2, rels, bb1a, 6016, TTp);
        }
        // t2 = relu(TT @ W1b + b1b) — 1128 blocks, ~4 resident/CU: keep BM=128
        SB(stream, w1b, HH_, 1536, 64, S3C);
        GX<128, 64>(stream, TTp, 6016, S3C, 1536, 64, T_N, bb1b, 1,
                    T2, 1536, nullptr, 0, nullptr, nullptr, nullptr);
        // pooling
        hipMemsetAsync(PO, 0, (size_t)O_N * HH_ * sizeof(float), stream);
        hipLaunchKernelGGL(scatter_pool, dim3(T_N), dim3(256), 0, stream, T2, rels, PO);
        {
            dim3 g(8, 64), b(256);
            pool_planes<<<g, b, 0, stream>>>(PO, CNT, 2048, PLp);
        }
        // obj MLP2 — BM=64: 256 blocks (was 128 = half the GPU idle)
        SB(stream, w2a, HH_, HH_, 64, S3B);
        GX<64, 64>(stream, PLp, 2048, S3B, HH_, 64, O_N, bb2a, 1,
                   nullptr, 0, Hp, 2048, nullptr, nullptr, nullptr);
        SB(stream, w2b, HH_, DG, 64, S3C);
        if (L < 4) {
            GX<64, 64>(stream, Hp, 2048, S3C, DG, 64, O_N, bb2b, 1,
                       nullptr, 0, OVp, 2048, nullptr, nullptr, nullptr);
            dim3 g(24, 64), b(256);
            predcopy_planes<<<g, b, 0, stream>>>(T2, 6016, PVp);
        } else {
            GX<64, 64>(stream, Hp, 2048, S3C, DG, 64, O_N, bb2b, 1,
                       out, DG, nullptr, 0, nullptr, nullptr, nullptr);
            hipLaunchKernelGGL(predcopy_f32, dim3((T_N * HH_ / 4 + 255) / 256),
                               dim3(256), 0, stream, T2, out + (size_t)O_N * DG);
        }
    }
}

// Round 3
// 2107.846 us; speedup vs baseline: 1.3378x; 1.0204x over previous
//
#include <hip/hip_runtime.h>

#define O_N 2000
#define T_N 6000
#define DIN 2048
#define DW  300
#define DG  512
#define HH_ 512

typedef __attribute__((ext_vector_type(8)))  short short8;
typedef __attribute__((ext_vector_type(16))) float f32x16;
typedef unsigned short u16;

__device__ __forceinline__ float4 ld4(const float* p) { return *(const float4*)p; }

// ---- bf16 split-3 helpers (RNE) ----
__device__ __forceinline__ u16 rbf(float x) {
    unsigned int u = __float_as_uint(x);
    u += 0x7FFFu + ((u >> 16) & 1u);
    return (u16)(u >> 16);
}
__device__ __forceinline__ float fbf(u16 h) {
    return __uint_as_float((unsigned int)h << 16);
}
__device__ __forceinline__ void split3(float x, short& h, short& m, short& l) {
    u16 a = rbf(x);
    float r = x - fbf(a);
    u16 b = rbf(r);
    r -= fbf(b);
    u16 c = rbf(r);
    h = (short)a; m = (short)b; l = (short)c;
}

// =====================================================================
// MFMA GEMM: C = act(A @ B + bias) with A,B given as 3 bf16 planes
// (hi/mid/lo), chunk-major layout [K/8][Mp][8] (A) / [K/8][N][8] (B).
// 6 MFMA products: hh -> acc_hi ; hm, mh, hl, mm, lh -> acc_lo.
// KS=0: 256 thr = 4 waves (2x2), wave tile (BM/2)x(BN/2).
// KS=1: 512 thr = 8 waves = 2 groups of 4; group g computes K-chunks
//   [g*h, g*h+h) (h = KC/2, requires KC%4==0) into registers with its
//   own double-buffered LDS pair; partials exchanged through LDS at the
//   end; epilogue split across groups (group g writes the fi=g half).
//   Rationale: 128x128 tile has 2.2x better LDS-bytes/flop than 64x64,
//   and in-block K-split gives grid=M/128*N/128 *1 block/CU* with 2
//   waves/SIMD and 775-cyc MFMA bursts -> compute-bound, no partial
//   HBM traffic, no extra workspace.
// Double-buffered LDS, one barrier per K=16 tile.
// Optional fp32 C out and/or bf16-plane out (for the next GEMM's A).
// Pair mode: gridDim.x doubled; bx >= nbx uses Bp2/C2/Op2.
// =====================================================================
template<int BM, int BN, int KS>
__global__ __launch_bounds__(KS ? 512 : 256, KS ? 2 : (BM == 64 ? 4 : 2))
void gemm_mx(
    const u16* __restrict__ Ap, int MpA,
    const u16* __restrict__ Bp, int N, int KC, int M,
    const float* __restrict__ bias, int doRelu,
    float* __restrict__ C, int ldc,
    u16* __restrict__ Op, int MpO,
    const u16* __restrict__ Bp2, float* __restrict__ C2, u16* __restrict__ Op2,
    int nbx)
{
    static_assert(BM == 128 || BM == 64, "BM in {64,128}");
    constexpr int WM = BM / 2, WN = BN / 2;
    constexpr int FI = WM / 32, FJ = WN / 32;
    static_assert(!KS || FI == 2, "KS path needs FI=2");
    constexpr int UA = 6 * BM;            // 16B staging units per tile (A)
    constexpr int UB = 6 * BN;
    constexpr int NI = (UA + UB) / 64;    // staging instructions per tile
    constexpr int II = (NI + 3) / 4;      // per wave (4 waves per group)
    constexpr int BUF = (BM + BN) * 48;   // ushorts per LDS buffer
    __shared__ u16 sm[(KS ? 4 : 2) * BUF];

    const int tid = threadIdx.x;
    const int w = tid >> 6, lane = tid & 63;
    const int wg = w & 3;                 // wave-in-group (== w when KS=0)
    const int g = KS ? (w >> 2) : 0;      // K-group
    const int ln31 = lane & 31, lq = lane >> 5;

    int bx = blockIdx.x;
    const u16* Bpl = Bp; float* Cl = C; u16* Opl = Op;
    if (bx >= nbx) { bx -= nbx; Bpl = Bp2; Cl = C2; Opl = Op2; }
    const int n0 = bx * BN, m0 = blockIdx.y * BM;
    const long psA = (long)KC * MpA * 8;  // full plane strides
    const long psB = (long)KC * N * 8;

    int c0 = 0, cn = KC;
    if (KS) { int h = (KC >> 2) << 1; c0 = g ? h : 0; cn = g ? (KC - h) : h; }
    const u16* ApG = Ap + (long)c0 * MpA * 8;
    const u16* BpG = Bpl + (long)c0 * N * 8;
    u16* smg = sm + g * 2 * BUF;

    // ---- staging assignment (per-wave instructions, 64 rows x 16B each) ----
    const u16* gb[II]; int gstep[II]; int lo[II]; bool gv[II];
#pragma unroll
    for (int ii = 0; ii < II; ii++) {
        int n = wg + 4 * ii;
        gv[ii] = n < NI;
        int nn = gv[ii] ? n : 0;
        int u0 = nn * 64;
        bool isA = u0 < UA;
        int uu = isA ? u0 : u0 - UA;
        int dim = isA ? BM : BN;
        int row0 = uu % dim, pq = uu / dim;
        int q = pq & 1, p = pq >> 1;
        const u16* pb = (isA ? ApG : BpG) + (long)p * (isA ? psA : psB);
        int mp = isA ? MpA : N;
        gb[ii] = pb + ((long)q * mp + (isA ? m0 : n0) + row0 + lane) * 8;
        gstep[ii] = mp * 16;              // ushorts per tile (2 chunks)
        // LDS dest mirrors the global source: per-lane row offset included.
        lo[ii] = (isA ? (pq * BM + row0) : (6 * BM + pq * BN + row0)) * 8 + lane * 8;
    }

    f32x16 ah[FI][FJ], al[FI][FJ];
#pragma unroll
    for (int fi = 0; fi < FI; fi++)
#pragma unroll
        for (int fj = 0; fj < FJ; fj++)
#pragma unroll
            for (int r = 0; r < 16; r++) { ah[fi][fj][r] = 0.f; al[fi][fj][r] = 0.f; }

    const int T = cn >> 1;                // equal across groups iff KC%4==0
    short8 pf[II];
#pragma unroll
    for (int ii = 0; ii < II; ii++) if (gv[ii]) pf[ii] = *(const short8*)(gb[ii]);
#pragma unroll
    for (int ii = 0; ii < II; ii++) if (gv[ii]) *(short8*)(smg + lo[ii]) = pf[ii];
    __syncthreads();

    for (int t = 0; t < T; t++) {
        const int cb = (t & 1) * BUF, nb2 = ((t + 1) & 1) * BUF;
        const bool more = (t + 1) < T;
        if (more) {
#pragma unroll
            for (int ii = 0; ii < II; ii++)
                if (gv[ii]) pf[ii] = *(const short8*)(gb[ii] + (long)(t + 1) * gstep[ii]);
        }
        const u16* ab = smg + cb;
        const u16* bb = ab + 6 * BM * 8;
        short8 af[FI][3];
#pragma unroll
        for (int fi = 0; fi < FI; fi++)
#pragma unroll
            for (int p = 0; p < 3; p++)
                af[fi][p] = *(const short8*)(ab + ((p * 2 + lq) * BM + (wg >> 1) * WM + fi * 32 + ln31) * 8);
#pragma unroll
        for (int fj = 0; fj < FJ; fj++) {
            const int rB = (wg & 1) * WN + fj * 32 + ln31;
            short8 bh = *(const short8*)(bb + ((0 * 2 + lq) * BN + rB) * 8);
            short8 bm_ = *(const short8*)(bb + ((1 * 2 + lq) * BN + rB) * 8);
            short8 bl = *(const short8*)(bb + ((2 * 2 + lq) * BN + rB) * 8);
#pragma unroll
            for (int fi = 0; fi < FI; fi++) {
                ah[fi][fj] = __builtin_amdgcn_mfma_f32_32x32x16_bf16(af[fi][0], bh,  ah[fi][fj], 0, 0, 0);
                al[fi][fj] = __builtin_amdgcn_mfma_f32_32x32x16_bf16(af[fi][0], bm_, al[fi][fj], 0, 0, 0);
                al[fi][fj] = __builtin_amdgcn_mfma_f32_32x32x16_bf16(af[fi][1], bh,  al[fi][fj], 0, 0, 0);
                al[fi][fj] = __builtin_amdgcn_mfma_f32_32x32x16_bf16(af[fi][0], bl,  al[fi][fj], 0, 0, 0);
                al[fi][fj] = __builtin_amdgcn_mfma_f32_32x32x16_bf16(af[fi][1], bm_, al[fi][fj], 0, 0, 0);
                al[fi][fj] = __builtin_amdgcn_mfma_f32_32x32x16_bf16(af[fi][2], bh,  al[fi][fj], 0, 0, 0);
            }
        }
        if (more) {
#pragma unroll
            for (int ii = 0; ii < II; ii++)
                if (gv[ii]) *(short8*)(smg + nb2 + lo[ii]) = pf[ii];
        }
        __syncthreads();
    }

    // ---- KS partial exchange: group g exports fi=(1-g), keeps fi=g ----
    // All register indexing is static inside wave-uniform branches (rule #20).
    float tv[FJ][16];
    if (KS) {
        constexpr int XW = FJ * 16 * 64;                 // floats per wave export
        float* xs = (float*)sm;
        float* wrp = xs + (1 - g) * 4 * XW + wg * XW;    // region for fi=(1-g)
        if (g == 0) {
#pragma unroll
            for (int fj = 0; fj < FJ; fj++)
#pragma unroll
                for (int r = 0; r < 16; r++)
                    wrp[(fj * 16 + r) * 64 + lane] = ah[1][fj][r] + al[1][fj][r];
        } else {
#pragma unroll
            for (int fj = 0; fj < FJ; fj++)
#pragma unroll
                for (int r = 0; r < 16; r++)
                    wrp[(fj * 16 + r) * 64 + lane] = ah[0][fj][r] + al[0][fj][r];
        }
        __syncthreads();
        float* rdp = xs + g * 4 * XW + wg * XW;          // partner's export of fi=g
        if (g == 0) {
#pragma unroll
            for (int fj = 0; fj < FJ; fj++)
#pragma unroll
                for (int r = 0; r < 16; r++)
                    tv[fj][r] = ah[0][fj][r] + al[0][fj][r] + rdp[(fj * 16 + r) * 64 + lane];
        } else {
#pragma unroll
            for (int fj = 0; fj < FJ; fj++)
#pragma unroll
                for (int r = 0; r < 16; r++)
                    tv[fj][r] = ah[1][fj][r] + al[1][fj][r] + rdp[(fj * 16 + r) * 64 + lane];
        }
        __syncthreads();   // exchange fully read before bounce reuses sm
    }

    // ---- epilogue (KS: wave writes only its fi==g half; 8 waves x 2 tiles) ----
    float* bounce = (float*)sm + w * 1184;     // 32x36 floats, per-wave region
    const long psO = (long)N * MpO;            // ushorts per out plane
#pragma unroll
    for (int fi = 0; fi < FI; fi++) {
        if (KS && fi != g) continue;
#pragma unroll
        for (int fj = 0; fj < FJ; fj++) {
            const int colBase = n0 + (wg & 1) * WN + fj * 32;
            const int rowBase = m0 + (wg >> 1) * WM + fi * 32;
            float bv = bias ? bias[colBase + ln31] : 0.f;
            float v[16];
#pragma unroll
            for (int r = 0; r < 16; r++) {
                float s = KS ? tv[fj][r] : (ah[fi][fj][r] + al[fi][fj][r]);
                float x = s + bv;
                if (doRelu) x = fmaxf(x, 0.f);
                v[r] = x;
            }
            if (Cl) {
#pragma unroll
                for (int r = 0; r < 16; r++) {
                    int row = rowBase + (r & 3) + 8 * (r >> 2) + 4 * lq;
                    if (row < M)
                        Cl[(long)row * ldc + colBase + ln31] = v[r];
                }
            }
            if (Opl) {
#pragma unroll
                for (int r = 0; r < 16; r++)
                    bounce[((r & 3) + 8 * (r >> 2) + 4 * lq) * 36 + ln31] = v[r];
#pragma unroll
                for (int u = 0; u < 2; u++) {
                    int urow = ln31, uc = lq + 2 * u;
                    const float* rp = bounce + urow * 36 + uc * 8;
                    short8 h8, m8, l8;
#pragma unroll
                    for (int j = 0; j < 8; j++) {
                        short a, b, c2; split3(rp[j], a, b, c2);
                        h8[j] = a; m8[j] = b; l8[j] = c2;
                    }
                    long cIdx = (long)((colBase + uc * 8) >> 3);
                    long base = (cIdx * MpO + rowBase + urow) * 8;
                    *(short8*)(Opl + base) = h8;
                    *(short8*)(Opl + psO + base) = m8;
                    *(short8*)(Opl + 2 * psO + base) = l8;
                }
            }
        }
    }
}

// ---- split weights: W [K][N] fp32 -> 3 planes [K/8][N][8] bf16 ----
__global__ __launch_bounds__(256) void split_b(
    const float* __restrict__ W, int K, int N, int KC,
    u16* __restrict__ Op)
{
    __shared__ float tl[64][65];
    const int tid = threadIdx.x;
    const int n0 = blockIdx.x * 64, k0 = blockIdx.y * 64;
    const long ps = (long)KC * N * 8;
#pragma unroll
    for (int l = 0; l < 4; l++) {
        int k = (tid >> 4) + l * 16;
        int nn = (tid & 15) << 2;
        float4 v = make_float4(0.f, 0.f, 0.f, 0.f);
        if (k0 + k < K) v = ld4(W + (long)(k0 + k) * N + n0 + nn);
        tl[k][nn] = v.x; tl[k][nn + 1] = v.y; tl[k][nn + 2] = v.z; tl[k][nn + 3] = v.w;
    }
    __syncthreads();
#pragma unroll
    for (int l = 0; l < 2; l++) {
        int u = tid + l * 256;
        int n = u & 63, c = u >> 6;
        short8 h8, m8, l8;
#pragma unroll
        for (int j = 0; j < 8; j++) {
            short a, b, c2; split3(tl[c * 8 + j][n], a, b, c2);
            h8[j] = a; m8[j] = b; l8[j] = c2;
        }
        long base = ((long)(k0 / 8 + c) * N + n0 + n) * 8;
        *(short8*)(Op + base) = h8;
        *(short8*)(Op + ps + base) = m8;
        *(short8*)(Op + 2 * ps + base) = l8;
    }
}

__device__ __forceinline__ void store_planes(u16* Op, long ps, long base, const float* x)
{
    short8 h8, m8, l8;
#pragma unroll
    for (int j = 0; j < 8; j++) {
        short a, b, c2; split3(x[j], a, b, c2);
        h8[j] = a; m8[j] = b; l8[j] = c2;
    }
    *(short8*)(Op + base) = h8;
    *(short8*)(Op + ps + base) = m8;
    *(short8*)(Op + 2 * ps + base) = l8;
}

// ---- concat(A | Tab[idx]) fp32 -> planes [KC][Mp][8] ----
__global__ __launch_bounds__(256) void split_concat_a(
    const float* __restrict__ E, int ldE, int KA,
    const float* __restrict__ Tab, int DWc,
    const int* __restrict__ idx, int idxStride,
    int mBase, int Mvalid, int Mp, int KC,
    u16* __restrict__ Op)
{
    int m = blockIdx.x * 256 + threadIdx.x;
    if (m >= Mp) return;
    int c = blockIdx.y;
    int gm = mBase + m;
    float x[8];
    if (gm >= Mvalid) {
#pragma unroll
        for (int j = 0; j < 8; j++) x[j] = 0.f;
    } else {
        int k0 = c * 8;
        if (k0 + 8 <= KA) {
            float4 a = ld4(E + (long)gm * ldE + k0);
            float4 b = ld4(E + (long)gm * ldE + k0 + 4);
            x[0] = a.x; x[1] = a.y; x[2] = a.z; x[3] = a.w;
            x[4] = b.x; x[5] = b.y; x[6] = b.z; x[7] = b.w;
        } else {
            const float* tr = Tab + (long)idx[(long)gm * idxStride] * DWc;
#pragma unroll
            for (int j = 0; j < 8; j++) {
                int k = k0 + j;
                x[j] = (k < KA) ? E[(long)gm * ldE + k]
                                : ((k - KA) < DWc ? tr[k - KA] : 0.f);
            }
        }
    }
    store_planes(Op, (long)KC * Mp * 8, ((long)c * Mp + m) * 8, x);
}

// ---- edge combine: relu(P1[s]+PP+P2[o]+b1a) -> planes (KC=64) ----
__global__ __launch_bounds__(256) void edge_planes(
    const float* __restrict__ PPv, const float* __restrict__ P1v,
    const float* __restrict__ P2v, const int* __restrict__ rels,
    const float* __restrict__ b1a, int Mp, u16* __restrict__ Op)
{
    int m = blockIdx.x * 256 + threadIdx.x;
    if (m >= Mp) return;
    int c = blockIdx.y;
    float x[8];
    if (m >= T_N) {
#pragma unroll
        for (int j = 0; j < 8; j++) x[j] = 0.f;
    } else {
        int s = rels[3 * m], o = rels[3 * m + 2];
        const float* pp = PPv + (long)m * HH_ + c * 8;
        const float* p1 = P1v + (long)s * HH_ + c * 8;
        const float* p2 = P2v + (long)o * HH_ + c * 8;
        const float* bb = b1a + c * 8;
#pragma unroll
        for (int j = 0; j < 8; j++)
            x[j] = fmaxf(pp[j] + p1[j] + p2[j] + bb[j], 0.f);
    }
    store_planes(Op, (long)64 * Mp * 8, ((long)c * Mp + m) * 8, x);
}

// ---- pooled/cnt -> planes (KC=64) ----
__global__ __launch_bounds__(256) void pool_planes(
    const float* __restrict__ PO, const int* __restrict__ CNT,
    int Mp, u16* __restrict__ Op)
{
    int m = blockIdx.x * 256 + threadIdx.x;
    if (m >= Mp) return;
    int c = blockIdx.y;
    float x[8];
    if (m >= O_N) {
#pragma unroll
        for (int j = 0; j < 8; j++) x[j] = 0.f;
    } else {
        int cc = CNT[m]; float cf = 1.f / (float)(cc < 1 ? 1 : cc);
#pragma unroll
        for (int j = 0; j < 8; j++) x[j] = PO[(long)m * HH_ + c * 8 + j] * cf;
    }
    store_planes(Op, (long)64 * Mp * 8, ((long)c * Mp + m) * 8, x);
}

// ---- T2 mid slice -> PV planes (KC=64) ----
__global__ __launch_bounds__(256) void predcopy_planes(
    const float* __restrict__ T2, int Mp, u16* __restrict__ Op)
{
    int m = blockIdx.x * 256 + threadIdx.x;
    if (m >= Mp) return;
    int c = blockIdx.y;
    float x[8];
    if (m >= T_N) {
#pragma unroll
        for (int j = 0; j < 8; j++) x[j] = 0.f;
    } else {
#pragma unroll
        for (int j = 0; j < 8; j++) x[j] = T2[(long)m * 1536 + 512 + c * 8 + j];
    }
    store_planes(Op, (long)64 * Mp * 8, ((long)c * Mp + m) * 8, x);
}

__global__ void predcopy_f32(const float* __restrict__ T2, float* __restrict__ dst)
{
    int i = blockIdx.x * 256 + threadIdx.x;   // float4 index
    if (i >= T_N * HH_ / 4) return;
    int e = i / (HH_ / 4);
    int j = (i % (HH_ / 4)) << 2;
    float4 v = ld4(T2 + (long)e * 1536 + 512 + j);
    *(float4*)(dst + (long)e * HH_ + j) = v;
}

__global__ void count_edges(const int* __restrict__ rels, int* __restrict__ CNT)
{
    int e = blockIdx.x * 256 + threadIdx.x;
    if (e >= T_N) return;
    atomicAdd(CNT + rels[3 * e + 0], 1);
    atomicAdd(CNT + rels[3 * e + 2], 1);
}

__global__ void scatter_pool(const float* __restrict__ T2,
                             const int* __restrict__ rels,
                             float* __restrict__ PO)
{
    int e = blockIdx.x;
    int t = threadIdx.x;            // 256
    int s = rels[e * 3 + 0];
    int o = rels[e * 3 + 2];
#pragma unroll
    for (int u = 0; u < 2; u++) {
        int j = t + u * 256;
        unsafeAtomicAdd(PO + (long)s * HH_ + j, T2[(long)e * 1536 + j]);
        unsafeAtomicAdd(PO + (long)o * HH_ + j, T2[(long)e * 1536 + 1024 + j]);
    }
}

// ---- host-side helpers ----
template<int BM, int BN>
static inline void GX(hipStream_t st, const u16* Ap, int MpA,
                      const u16* Bp, int N, int KC, int M,
                      const float* bias, int relu_,
                      float* C, int ldc, u16* Op, int MpO,
                      const u16* Bp2, float* C2, u16* Op2)
{
    int nbx = N / BN;
    int pair = (Bp2 != nullptr) ? 2 : 1;
    dim3 g(nbx * pair, MpA / BM), b(256);
    gemm_mx<BM, BN, 0><<<g, b, 0, st>>>(Ap, MpA, Bp, N, KC, M, bias, relu_,
                                        C, ldc, Op, MpO, Bp2, C2, Op2, nbx);
}

// in-block K-split launch (512 threads, KC%4==0 required)
template<int BM, int BN>
static inline void GK2(hipStream_t st, const u16* Ap, int MpA,
                       const u16* Bp, int N, int KC, int M,
                       const float* bias, int relu_,
                       float* C, int ldc, u16* Op, int MpO)
{
    dim3 g(N / BN, MpA / BM), b(512);
    gemm_mx<BM, BN, 1><<<g, b, 0, st>>>(Ap, MpA, Bp, N, KC, M, bias, relu_,
                                        C, ldc, Op, MpO,
                                        nullptr, nullptr, nullptr, N / BN);
}

static inline void SB(hipStream_t st, const float* W, int K, int N, int KC, u16* Op)
{
    dim3 g(N / 64, KC / 8), b(256);
    split_b<<<g, b, 0, st>>>(W, K, N, KC, Op);
}

extern "C" void kernel_launch(void* const* d_in, const int* in_sizes, int n_in,
                              void* d_out, int out_size, void* d_ws, size_t ws_size,
                              hipStream_t stream)
{
    const float* obj_embs  = (const float*)d_in[0];
    const float* pred_embs = (const float*)d_in[2];
    const int*   rels      = (const int*)d_in[4];
    const int*   objs      = (const int*)d_in[5];
    const float* obj_table = (const float*)d_in[6];
    const float* rel_table = (const float*)d_in[7];
    const float* Wf_obj = (const float*)d_in[8];
    const float* bf_obj = (const float*)d_in[9];
    const float* Wf_rel = (const float*)d_in[10];
    const float* bf_rel = (const float*)d_in[11];
    const float* W1a = (const float*)d_in[12];
    const float* b1a = (const float*)d_in[13];
    const float* W1b = (const float*)d_in[14];
    const float* b1b = (const float*)d_in[15];
    const float* W2a = (const float*)d_in[16];
    const float* b2a = (const float*)d_in[17];
    const float* W2b = (const float*)d_in[18];
    const float* b2b = (const float*)d_in[19];
    const float* Ws1a = (const float*)d_in[20];
    const float* bs1a = (const float*)d_in[21];
    const float* Ws1b = (const float*)d_in[22];
    const float* bs1b = (const float*)d_in[23];
    const float* Ws2a = (const float*)d_in[24];
    const float* bs2a = (const float*)d_in[25];
    const float* Ws2b = (const float*)d_in[26];
    const float* bs2b = (const float*)d_in[27];
    float* out = (float*)d_out;

    // ---- workspace layout (bytes), total ~119.6 MB ----
    unsigned char* B8 = (unsigned char*)d_ws;
    constexpr size_t S1O  = 0;                     // concat-A planes    29,097,984
    constexpr size_t S2O  = 29097984;              // chunk-out planes   25,165,824
    constexpr size_t S3AO = 54263808;              // Wf B planes        29,097,984
    constexpr size_t ZSZ  = 86507520;              // overlay-zone size
    //   overlays inside zone (live only after L0's PP GEMM):
    constexpr size_t T2O  = 0;                     // 36,864,000
    constexpr size_t TTO  = 36864000;              // 18,481,152 (TTp / Hp)
    constexpr size_t PVO  = 55345152;              // 18,481,152 (PVpS)
    constexpr size_t PLO  = 73826304;              //  6,291,456 (PLp)
    constexpr size_t OVO  = 80117760;              //  6,291,456 (OVpS)
    constexpr size_t S3BO = ZSZ;                   //  6,291,456 (B slot b)
    constexpr size_t S3CO = S3BO + 6291456;        //  6,291,456 (B slot c)
    constexpr size_t PPO  = S3CO + 6291456;        // 12,288,000
    constexpr size_t P1O  = PPO + 12288000;        //  4,096,000 (also PO)
    constexpr size_t P2O  = P1O + 4096000;         //  4,096,000
    constexpr size_t CNO  = P2O + 4096000;         //  8,000

    u16* S1  = (u16*)(B8 + S1O);
    u16* S2  = (u16*)(B8 + S2O);
    u16* S3A = (u16*)(B8 + S3AO);
    u16* S3B = (u16*)(B8 + S3BO);
    u16* S3C = (u16*)(B8 + S3CO);
    float* T2 = (float*)(B8 + T2O);
    u16* TTp  = (u16*)(B8 + TTO);
    u16* Hp   = (u16*)(B8 + TTO);                 // overlays TTp (disjoint in time)
    u16* PVp  = (u16*)(B8 + PVO);
    u16* PLp  = (u16*)(B8 + PLO);
    u16* OVp  = (u16*)(B8 + OVO);
    float* PP = (float*)(B8 + PPO);
    float* P1 = (float*)(B8 + P1O);
    float* P2 = (float*)(B8 + P2O);
    float* PO = P1;                                // reuse (P1 dead after edge)
    int* CNT  = (int*)(B8 + CNO);

    // ---- edge counts (fixed for whole call) ----
    hipMemsetAsync(CNT, 0, O_N * sizeof(int), stream);
    hipLaunchKernelGGL(count_edges, dim3((T_N + 255) / 256), dim3(256), 0, stream, rels, CNT);

    // ================= projections + layer-0 front =================
    // obj: OV-chunk planes -> P1/P2 via W1a top/bot
    SB(stream, Wf_obj, DIN + DW, DIN, 296, S3A);
    {
        dim3 g(8, 296), b(256);
        split_concat_a<<<g, b, 0, stream>>>(obj_embs, DIN, DIN, obj_table, DW,
                                            objs, 1, 0, O_N, 2048, 296, S1);
    }
    // in-block K-split 128x128: grid 256 @ 512 thr, compute-bound regime
    GK2<128, 128>(stream, S1, 2048, S3A, DIN, 296, O_N, bf_obj, 1,
                  nullptr, 0, S2, 2048);
    SB(stream, W1a, DIN, HH_, 256, S3B);                       // top (L0 K=2048)
    SB(stream, W1a + (size_t)2 * DIN * HH_, DIN, HH_, 256, S3C); // bot
    GX<64, 64>(stream, S2, 2048, S3B, HH_, 256, O_N, nullptr, 0,
               P1, HH_, nullptr, 0, S3C, P2, nullptr);
    // pred, M-chunked: proj -> PV-chunk planes -> PP via W1a mid
    SB(stream, Wf_rel, DIN + DW, DIN, 296, S3A);
    SB(stream, W1a + (size_t)DIN * HH_, DIN, HH_, 256, S3B);   // mid
    for (int ch = 0; ch < 3; ch++) {
        int ch0 = ch * 2048;
        int mp  = (ch == 2) ? 1920 : 2048;
        int mv  = (ch == 2) ? 1904 : 2048;
        dim3 g((mp + 255) / 256, 296), b(256);
        split_concat_a<<<g, b, 0, stream>>>(pred_embs, DIN, DIN, rel_table, DW,
                                            rels + 1, 3, ch0, T_N, mp, 296, S1);
        GK2<128, 128>(stream, S1, mp, S3A, DIN, 296, mv, bf_rel, 1,
                      nullptr, 0, S2, mp);
        GX<64, 64>(stream, S2, mp, S3B, HH_, 256, mv, nullptr, 0,
                   PP + (size_t)ch0 * HH_, HH_, nullptr, 0,
                   nullptr, nullptr, nullptr);
    }

    // ================= 5 conv layers =================
    for (int L = 0; L < 5; L++) {
        const float* bb1a = (L == 0) ? b1a : (bs1a + (size_t)(L - 1) * HH_);
        const float* w1b  = (L == 0) ? W1b : (Ws1b + (size_t)(L - 1) * HH_ * 1536);
        const float* bb1b = (L == 0) ? b1b : (bs1b + (size_t)(L - 1) * 1536);
        const float* w2a  = (L == 0) ? W2a : (Ws2a + (size_t)(L - 1) * HH_ * HH_);
        const float* bb2a = (L == 0) ? b2a : (bs2a + (size_t)(L - 1) * HH_);
        const float* w2b  = (L == 0) ? W2b : (Ws2b + (size_t)(L - 1) * HH_ * DG);
        const float* bb2b = (L == 0) ? b2b : (bs2b + (size_t)(L - 1) * DG);

        if (L > 0) {
            const float* w1a = Ws1a + (size_t)(L - 1) * 3 * HH_ * HH_;
            SB(stream, w1a, HH_, HH_, 64, S3B);                       // top
            SB(stream, w1a + (size_t)2 * HH_ * HH_, HH_, HH_, 64, S3C); // bot
            GX<64, 64>(stream, OVp, 2048, S3B, HH_, 64, O_N, nullptr, 0,
                       P1, HH_, nullptr, 0, S3C, P2, nullptr);
            SB(stream, w1a + (size_t)HH_ * HH_, HH_, HH_, 64, S3B);   // mid
            GX<64, 64>(stream, PVp, 6016, S3B, HH_, 64, T_N, nullptr, 0,
                       PP, HH_, nullptr, 0, nullptr, nullptr, nullptr);
        }

        // edge combine -> TT planes
        {
            dim3 g(24, 64), b(256);
            edge_planes<<<g, b, 0, stream>>>(PP, P1, P2, rels, bb1a, 6016, TTp);
        }
        // t2 = relu(TT @ W1b + b1b) — 564 blocks, 3 resident/CU, best LDS/flop
        SB(stream, w1b, HH_, 1536, 64, S3C);
        GX<128, 128>(stream, TTp, 6016, S3C, 1536, 64, T_N, bb1b, 1,
                     T2, 1536, nullptr, 0, nullptr, nullptr, nullptr);
        // pooling
        hipMemsetAsync(PO, 0, (size_t)O_N * HH_ * sizeof(float), stream);
        hipLaunchKernelGGL(scatter_pool, dim3(T_N), dim3(256), 0, stream, T2, rels, PO);
        {
            dim3 g(8, 64), b(256);
            pool_planes<<<g, b, 0, stream>>>(PO, CNT, 2048, PLp);
        }
        // obj MLP2
        SB(stream, w2a, HH_, HH_, 64, S3B);
        GX<64, 64>(stream, PLp, 2048, S3B, HH_, 64, O_N, bb2a, 1,
                   nullptr, 0, Hp, 2048, nullptr, nullptr, nullptr);
        SB(stream, w2b, HH_, DG, 64, S3C);
        if (L < 4) {
            GX<64, 64>(stream, Hp, 2048, S3C, DG, 64, O_N, bb2b, 1,
                       nullptr, 0, OVp, 2048, nullptr, nullptr, nullptr);
            dim3 g(24, 64), b(256);
            predcopy_planes<<<g, b, 0, stream>>>(T2, 6016, PVp);
        } else {
            GX<64, 64>(stream, Hp, 2048, S3C, DG, 64, O_N, bb2b, 1,
                       out, DG, nullptr, 0, nullptr, nullptr, nullptr);
            hipLaunchKernelGGL(predcopy_f32, dim3((T_N * HH_ / 4 + 255) / 256),
                               dim3(256), 0, stream, T2, out + (size_t)O_N * DG);
        }
    }
}

// Round 4
// 2011.399 us; speedup vs baseline: 1.4020x; 1.0480x over previous
//
#include <hip/hip_runtime.h>

#define O_N 2000
#define T_N 6000
#define DIN 2048
#define DW  300
#define DG  512
#define HH_ 512

typedef __attribute__((ext_vector_type(8)))  short short8;
typedef __attribute__((ext_vector_type(16))) float f32x16;
typedef unsigned short u16;

__device__ __forceinline__ float4 ld4(const float* p) { return *(const float4*)p; }

// ---- bf16 split-3 helpers (RNE) ----
__device__ __forceinline__ u16 rbf(float x) {
    unsigned int u = __float_as_uint(x);
    u += 0x7FFFu + ((u >> 16) & 1u);
    return (u16)(u >> 16);
}
__device__ __forceinline__ float fbf(u16 h) {
    return __uint_as_float((unsigned int)h << 16);
}
__device__ __forceinline__ void split3(float x, short& h, short& m, short& l) {
    u16 a = rbf(x);
    float r = x - fbf(a);
    u16 b = rbf(r);
    r -= fbf(b);
    u16 c = rbf(r);
    h = (short)a; m = (short)b; l = (short)c;
}

// ---- async global->LDS, 16B per lane (wave-uniform LDS base) ----
// HW semantics: writes lds_base + lane*16; global src is per-lane.
// Our LDS layout is exactly linear in lane order (base + lane*16B), so
// this is a drop-in replacement for the former global->reg->ds_write
// staging (rule: both sides linear / neither swizzled).
__device__ __forceinline__ void gl_lds16(u16* lds, const u16* g) {
    auto* gp = (const __attribute__((address_space(1))) unsigned int*)g;
    auto* lp = (__attribute__((address_space(3))) unsigned int*)lds;
    __builtin_amdgcn_global_load_lds(gp, lp, 16, 0, 0);
}

// =====================================================================
// MFMA GEMM: C = act(A @ B + bias) with A,B given as 3 bf16 planes
// (hi/mid/lo), chunk-major layout [K/8][Mp][8] (A) / [K/8][N][8] (B).
// 6 MFMA products: hh -> acc_hi ; hm, mh, hl, mm, lh -> acc_lo.
// KS=0: 256 thr = 4 waves (2x2), wave tile (BM/2)x(BN/2).
// KS=1: 512 thr = 8 waves = 2 groups of 4; group g computes K-chunks
//   [g*h, g*h+h) into registers with its own double-buffered LDS pair;
//   partials exchanged through LDS at the end; epilogue split.
// Staging: __builtin_amdgcn_global_load_lds width=16 (no VGPR round
// trip, no ds_write issue, no vmcnt->ds_write->lgkm double drain).
// Double-buffered LDS, one barrier per K=16 tile.
// Optional fp32 C out and/or bf16-plane out (for the next GEMM's A).
// Pair mode: gridDim.x doubled; bx >= nbx uses Bp2/C2/Op2.
// =====================================================================
template<int BM, int BN, int KS>
__global__ __launch_bounds__(KS ? 512 : 256, KS ? 2 : (BM == 64 ? 4 : 2))
void gemm_mx(
    const u16* __restrict__ Ap, int MpA,
    const u16* __restrict__ Bp, int N, int KC, int M,
    const float* __restrict__ bias, int doRelu,
    float* __restrict__ C, int ldc,
    u16* __restrict__ Op, int MpO,
    const u16* __restrict__ Bp2, float* __restrict__ C2, u16* __restrict__ Op2,
    int nbx)
{
    static_assert(BM == 128 || BM == 64, "BM in {64,128}");
    constexpr int WM = BM / 2, WN = BN / 2;
    constexpr int FI = WM / 32, FJ = WN / 32;
    static_assert(!KS || FI == 2, "KS path needs FI=2");
    constexpr int UA = 6 * BM;            // 16B staging units per tile (A)
    constexpr int UB = 6 * BN;
    constexpr int NI = (UA + UB) / 64;    // staging instructions per tile
    constexpr int II = (NI + 3) / 4;      // per wave (4 waves per group)
    constexpr int BUF = (BM + BN) * 48;   // ushorts per LDS buffer
    __shared__ u16 sm[(KS ? 4 : 2) * BUF];

    const int tid = threadIdx.x;
    const int w = tid >> 6, lane = tid & 63;
    const int wg = w & 3;                 // wave-in-group (== w when KS=0)
    const int g = KS ? (w >> 2) : 0;      // K-group
    const int ln31 = lane & 31, lq = lane >> 5;

    int bx = blockIdx.x;
    const u16* Bpl = Bp; float* Cl = C; u16* Opl = Op;
    if (bx >= nbx) { bx -= nbx; Bpl = Bp2; Cl = C2; Opl = Op2; }
    const int n0 = bx * BN, m0 = blockIdx.y * BM;
    const long psA = (long)KC * MpA * 8;  // full plane strides
    const long psB = (long)KC * N * 8;

    int c0 = 0, cn = KC;
    if (KS) { int h = (KC >> 2) << 1; c0 = g ? h : 0; cn = g ? (KC - h) : h; }
    const u16* ApG = Ap + (long)c0 * MpA * 8;
    const u16* BpG = Bpl + (long)c0 * N * 8;
    u16* smg = sm + g * 2 * BUF;

    // ---- staging assignment (per-wave instructions, 64 rows x 16B each) ----
    // gb[] carries the per-lane global source; lob[] is the wave-uniform
    // LDS base (HW adds lane*16).
    const u16* gb[II]; int gstep[II]; int lob[II]; bool gv[II];
#pragma unroll
    for (int ii = 0; ii < II; ii++) {
        int n = wg + 4 * ii;
        gv[ii] = n < NI;
        int nn = gv[ii] ? n : 0;
        int u0 = nn * 64;
        bool isA = u0 < UA;
        int uu = isA ? u0 : u0 - UA;
        int dim = isA ? BM : BN;
        int row0 = uu % dim, pq = uu / dim;
        int q = pq & 1, p = pq >> 1;
        const u16* pb = (isA ? ApG : BpG) + (long)p * (isA ? psA : psB);
        int mp = isA ? MpA : N;
        gb[ii] = pb + ((long)q * mp + (isA ? m0 : n0) + row0 + lane) * 8;
        gstep[ii] = mp * 16;              // ushorts per tile (2 chunks)
        lob[ii] = (isA ? (pq * BM + row0) : (6 * BM + pq * BN + row0)) * 8;
    }

    f32x16 ah[FI][FJ], al[FI][FJ];
#pragma unroll
    for (int fi = 0; fi < FI; fi++)
#pragma unroll
        for (int fj = 0; fj < FJ; fj++)
#pragma unroll
            for (int r = 0; r < 16; r++) { ah[fi][fj][r] = 0.f; al[fi][fj][r] = 0.f; }

    const int T = cn >> 1;                // equal across groups iff KC%4==0
    // prologue: async-stage tile 0 into buffer 0 (vmcnt drained by barrier)
#pragma unroll
    for (int ii = 0; ii < II; ii++)
        if (gv[ii]) gl_lds16(smg + lob[ii], gb[ii]);
    __syncthreads();

    for (int t = 0; t < T; t++) {
        const int cb = (t & 1) * BUF, nb2 = ((t + 1) & 1) * BUF;
        if (t + 1 < T) {
            // async-stage next tile; latency hides under this tile's MFMA,
            // drained by the vmcnt(0) the compiler emits at the barrier.
#pragma unroll
            for (int ii = 0; ii < II; ii++)
                if (gv[ii]) gl_lds16(smg + nb2 + lob[ii],
                                     gb[ii] + (long)(t + 1) * gstep[ii]);
        }
        const u16* ab = smg + cb;
        const u16* bb = ab + 6 * BM * 8;
        short8 af[FI][3];
#pragma unroll
        for (int fi = 0; fi < FI; fi++)
#pragma unroll
            for (int p = 0; p < 3; p++)
                af[fi][p] = *(const short8*)(ab + ((p * 2 + lq) * BM + (wg >> 1) * WM + fi * 32 + ln31) * 8);
#pragma unroll
        for (int fj = 0; fj < FJ; fj++) {
            const int rB = (wg & 1) * WN + fj * 32 + ln31;
            short8 bh = *(const short8*)(bb + ((0 * 2 + lq) * BN + rB) * 8);
            short8 bm_ = *(const short8*)(bb + ((1 * 2 + lq) * BN + rB) * 8);
            short8 bl = *(const short8*)(bb + ((2 * 2 + lq) * BN + rB) * 8);
#pragma unroll
            for (int fi = 0; fi < FI; fi++) {
                ah[fi][fj] = __builtin_amdgcn_mfma_f32_32x32x16_bf16(af[fi][0], bh,  ah[fi][fj], 0, 0, 0);
                al[fi][fj] = __builtin_amdgcn_mfma_f32_32x32x16_bf16(af[fi][0], bm_, al[fi][fj], 0, 0, 0);
                al[fi][fj] = __builtin_amdgcn_mfma_f32_32x32x16_bf16(af[fi][1], bh,  al[fi][fj], 0, 0, 0);
                al[fi][fj] = __builtin_amdgcn_mfma_f32_32x32x16_bf16(af[fi][0], bl,  al[fi][fj], 0, 0, 0);
                al[fi][fj] = __builtin_amdgcn_mfma_f32_32x32x16_bf16(af[fi][1], bm_, al[fi][fj], 0, 0, 0);
                al[fi][fj] = __builtin_amdgcn_mfma_f32_32x32x16_bf16(af[fi][2], bh,  al[fi][fj], 0, 0, 0);
            }
        }
        __syncthreads();
    }

    // ---- KS partial exchange: group g exports fi=(1-g), keeps fi=g ----
    // All register indexing is static inside wave-uniform branches (rule #20).
    float tv[FJ][16];
    if (KS) {
        constexpr int XW = FJ * 16 * 64;                 // floats per wave export
        float* xs = (float*)sm;
        float* wrp = xs + (1 - g) * 4 * XW + wg * XW;    // region for fi=(1-g)
        if (g == 0) {
#pragma unroll
            for (int fj = 0; fj < FJ; fj++)
#pragma unroll
                for (int r = 0; r < 16; r++)
                    wrp[(fj * 16 + r) * 64 + lane] = ah[1][fj][r] + al[1][fj][r];
        } else {
#pragma unroll
            for (int fj = 0; fj < FJ; fj++)
#pragma unroll
                for (int r = 0; r < 16; r++)
                    wrp[(fj * 16 + r) * 64 + lane] = ah[0][fj][r] + al[0][fj][r];
        }
        __syncthreads();
        float* rdp = xs + g * 4 * XW + wg * XW;          // partner's export of fi=g
        if (g == 0) {
#pragma unroll
            for (int fj = 0; fj < FJ; fj++)
#pragma unroll
                for (int r = 0; r < 16; r++)
                    tv[fj][r] = ah[0][fj][r] + al[0][fj][r] + rdp[(fj * 16 + r) * 64 + lane];
        } else {
#pragma unroll
            for (int fj = 0; fj < FJ; fj++)
#pragma unroll
                for (int r = 0; r < 16; r++)
                    tv[fj][r] = ah[1][fj][r] + al[1][fj][r] + rdp[(fj * 16 + r) * 64 + lane];
        }
        __syncthreads();   // exchange fully read before bounce reuses sm
    }

    // ---- epilogue (KS: wave writes only its fi==g half; 8 waves x 2 tiles) ----
    float* bounce = (float*)sm + w * 1184;     // 32x36 floats, per-wave region
    const long psO = (long)N * MpO;            // ushorts per out plane
#pragma unroll
    for (int fi = 0; fi < FI; fi++) {
        if (KS && fi != g) continue;
#pragma unroll
        for (int fj = 0; fj < FJ; fj++) {
            const int colBase = n0 + (wg & 1) * WN + fj * 32;
            const int rowBase = m0 + (wg >> 1) * WM + fi * 32;
            float bv = bias ? bias[colBase + ln31] : 0.f;
            float v[16];
#pragma unroll
            for (int r = 0; r < 16; r++) {
                float s = KS ? tv[fj][r] : (ah[fi][fj][r] + al[fi][fj][r]);
                float x = s + bv;
                if (doRelu) x = fmaxf(x, 0.f);
                v[r] = x;
            }
            if (Cl) {
#pragma unroll
                for (int r = 0; r < 16; r++) {
                    int row = rowBase + (r & 3) + 8 * (r >> 2) + 4 * lq;
                    if (row < M)
                        Cl[(long)row * ldc + colBase + ln31] = v[r];
                }
            }
            if (Opl) {
#pragma unroll
                for (int r = 0; r < 16; r++)
                    bounce[((r & 3) + 8 * (r >> 2) + 4 * lq) * 36 + ln31] = v[r];
#pragma unroll
                for (int u = 0; u < 2; u++) {
                    int urow = ln31, uc = lq + 2 * u;
                    const float* rp = bounce + urow * 36 + uc * 8;
                    short8 h8, m8, l8;
#pragma unroll
                    for (int j = 0; j < 8; j++) {
                        short a, b, c2; split3(rp[j], a, b, c2);
                        h8[j] = a; m8[j] = b; l8[j] = c2;
                    }
                    long cIdx = (long)((colBase + uc * 8) >> 3);
                    long base = (cIdx * MpO + rowBase + urow) * 8;
                    *(short8*)(Opl + base) = h8;
                    *(short8*)(Opl + psO + base) = m8;
                    *(short8*)(Opl + 2 * psO + base) = l8;
                }
            }
        }
    }
}

// ---- split weights: W [K][N] fp32 -> 3 planes [K/8][N][8] bf16 ----
__global__ __launch_bounds__(256) void split_b(
    const float* __restrict__ W, int K, int N, int KC,
    u16* __restrict__ Op)
{
    __shared__ float tl[64][65];
    const int tid = threadIdx.x;
    const int n0 = blockIdx.x * 64, k0 = blockIdx.y * 64;
    const long ps = (long)KC * N * 8;
#pragma unroll
    for (int l = 0; l < 4; l++) {
        int k = (tid >> 4) + l * 16;
        int nn = (tid & 15) << 2;
        float4 v = make_float4(0.f, 0.f, 0.f, 0.f);
        if (k0 + k < K) v = ld4(W + (long)(k0 + k) * N + n0 + nn);
        tl[k][nn] = v.x; tl[k][nn + 1] = v.y; tl[k][nn + 2] = v.z; tl[k][nn + 3] = v.w;
    }
    __syncthreads();
#pragma unroll
    for (int l = 0; l < 2; l++) {
        int u = tid + l * 256;
        int n = u & 63, c = u >> 6;
        short8 h8, m8, l8;
#pragma unroll
        for (int j = 0; j < 8; j++) {
            short a, b, c2; split3(tl[c * 8 + j][n], a, b, c2);
            h8[j] = a; m8[j] = b; l8[j] = c2;
        }
        long base = ((long)(k0 / 8 + c) * N + n0 + n) * 8;
        *(short8*)(Op + base) = h8;
        *(short8*)(Op + ps + base) = m8;
        *(short8*)(Op + 2 * ps + base) = l8;
    }
}

__device__ __forceinline__ void store_planes(u16* Op, long ps, long base, const float* x)
{
    short8 h8, m8, l8;
#pragma unroll
    for (int j = 0; j < 8; j++) {
        short a, b, c2; split3(x[j], a, b, c2);
        h8[j] = a; m8[j] = b; l8[j] = c2;
    }
    *(short8*)(Op + base) = h8;
    *(short8*)(Op + ps + base) = m8;
    *(short8*)(Op + 2 * ps + base) = l8;
}

// ---- concat(A | Tab[idx]) fp32 -> planes [KC][Mp][8] ----
__global__ __launch_bounds__(256) void split_concat_a(
    const float* __restrict__ E, int ldE, int KA,
    const float* __restrict__ Tab, int DWc,
    const int* __restrict__ idx, int idxStride,
    int mBase, int Mvalid, int Mp, int KC,
    u16* __restrict__ Op)
{
    int m = blockIdx.x * 256 + threadIdx.x;
    if (m >= Mp) return;
    int c = blockIdx.y;
    int gm = mBase + m;
    float x[8];
    if (gm >= Mvalid) {
#pragma unroll
        for (int j = 0; j < 8; j++) x[j] = 0.f;
    } else {
        int k0 = c * 8;
        if (k0 + 8 <= KA) {
            float4 a = ld4(E + (long)gm * ldE + k0);
            float4 b = ld4(E + (long)gm * ldE + k0 + 4);
            x[0] = a.x; x[1] = a.y; x[2] = a.z; x[3] = a.w;
            x[4] = b.x; x[5] = b.y; x[6] = b.z; x[7] = b.w;
        } else {
            const float* tr = Tab + (long)idx[(long)gm * idxStride] * DWc;
#pragma unroll
            for (int j = 0; j < 8; j++) {
                int k = k0 + j;
                x[j] = (k < KA) ? E[(long)gm * ldE + k]
                                : ((k - KA) < DWc ? tr[k - KA] : 0.f);
            }
        }
    }
    store_planes(Op, (long)KC * Mp * 8, ((long)c * Mp + m) * 8, x);
}

// ---- edge combine: relu(P1[s]+PP+P2[o]+b1a) -> planes (KC=64) ----
__global__ __launch_bounds__(256) void edge_planes(
    const float* __restrict__ PPv, const float* __restrict__ P1v,
    const float* __restrict__ P2v, const int* __restrict__ rels,
    const float* __restrict__ b1a, int Mp, u16* __restrict__ Op)
{
    int m = blockIdx.x * 256 + threadIdx.x;
    if (m >= Mp) return;
    int c = blockIdx.y;
    float x[8];
    if (m >= T_N) {
#pragma unroll
        for (int j = 0; j < 8; j++) x[j] = 0.f;
    } else {
        int s = rels[3 * m], o = rels[3 * m + 2];
        const float* pp = PPv + (long)m * HH_ + c * 8;
        const float* p1 = P1v + (long)s * HH_ + c * 8;
        const float* p2 = P2v + (long)o * HH_ + c * 8;
        const float* bb = b1a + c * 8;
#pragma unroll
        for (int j = 0; j < 8; j++)
            x[j] = fmaxf(pp[j] + p1[j] + p2[j] + bb[j], 0.f);
    }
    store_planes(Op, (long)64 * Mp * 8, ((long)c * Mp + m) * 8, x);
}

// ---- pooled/cnt -> planes (KC=64) ----
__global__ __launch_bounds__(256) void pool_planes(
    const float* __restrict__ PO, const int* __restrict__ CNT,
    int Mp, u16* __restrict__ Op)
{
    int m = blockIdx.x * 256 + threadIdx.x;
    if (m >= Mp) return;
    int c = blockIdx.y;
    float x[8];
    if (m >= O_N) {
#pragma unroll
        for (int j = 0; j < 8; j++) x[j] = 0.f;
    } else {
        int cc = CNT[m]; float cf = 1.f / (float)(cc < 1 ? 1 : cc);
#pragma unroll
        for (int j = 0; j < 8; j++) x[j] = PO[(long)m * HH_ + c * 8 + j] * cf;
    }
    store_planes(Op, (long)64 * Mp * 8, ((long)c * Mp + m) * 8, x);
}

// ---- T2 mid slice -> PV planes (KC=64) ----
__global__ __launch_bounds__(256) void predcopy_planes(
    const float* __restrict__ T2, int Mp, u16* __restrict__ Op)
{
    int m = blockIdx.x * 256 + threadIdx.x;
    if (m >= Mp) return;
    int c = blockIdx.y;
    float x[8];
    if (m >= T_N) {
#pragma unroll
        for (int j = 0; j < 8; j++) x[j] = 0.f;
    } else {
#pragma unroll
        for (int j = 0; j < 8; j++) x[j] = T2[(long)m * 1536 + 512 + c * 8 + j];
    }
    store_planes(Op, (long)64 * Mp * 8, ((long)c * Mp + m) * 8, x);
}

__global__ void predcopy_f32(const float* __restrict__ T2, float* __restrict__ dst)
{
    int i = blockIdx.x * 256 + threadIdx.x;   // float4 index
    if (i >= T_N * HH_ / 4) return;
    int e = i / (HH_ / 4);
    int j = (i % (HH_ / 4)) << 2;
    float4 v = ld4(T2 + (long)e * 1536 + 512 + j);
    *(float4*)(dst + (long)e * HH_ + j) = v;
}

__global__ void count_edges(const int* __restrict__ rels, int* __restrict__ CNT)
{
    int e = blockIdx.x * 256 + threadIdx.x;
    if (e >= T_N) return;
    atomicAdd(CNT + rels[3 * e + 0], 1);
    atomicAdd(CNT + rels[3 * e + 2], 1);
}

__global__ void scatter_pool(const float* __restrict__ T2,
                             const int* __restrict__ rels,
                             float* __restrict__ PO)
{
    int e = blockIdx.x;
    int t = threadIdx.x;            // 256
    int s = rels[e * 3 + 0];
    int o = rels[e * 3 + 2];
#pragma unroll
    for (int u = 0; u < 2; u++) {
        int j = t + u * 256;
        unsafeAtomicAdd(PO + (long)s * HH_ + j, T2[(long)e * 1536 + j]);
        unsafeAtomicAdd(PO + (long)o * HH_ + j, T2[(long)e * 1536 + 1024 + j]);
    }
}

// ---- host-side helpers ----
template<int BM, int BN>
static inline void GX(hipStream_t st, const u16* Ap, int MpA,
                      const u16* Bp, int N, int KC, int M,
                      const float* bias, int relu_,
                      float* C, int ldc, u16* Op, int MpO,
                      const u16* Bp2, float* C2, u16* Op2)
{
    int nbx = N / BN;
    int pair = (Bp2 != nullptr) ? 2 : 1;
    dim3 g(nbx * pair, MpA / BM), b(256);
    gemm_mx<BM, BN, 0><<<g, b, 0, st>>>(Ap, MpA, Bp, N, KC, M, bias, relu_,
                                        C, ldc, Op, MpO, Bp2, C2, Op2, nbx);
}

// in-block K-split launch (512 threads, KC%4==0 required)
template<int BM, int BN>
static inline void GK2(hipStream_t st, const u16* Ap, int MpA,
                       const u16* Bp, int N, int KC, int M,
                       const float* bias, int relu_,
                       float* C, int ldc, u16* Op, int MpO)
{
    dim3 g(N / BN, MpA / BM), b(512);
    gemm_mx<BM, BN, 1><<<g, b, 0, st>>>(Ap, MpA, Bp, N, KC, M, bias, relu_,
                                        C, ldc, Op, MpO,
                                        nullptr, nullptr, nullptr, N / BN);
}

static inline void SB(hipStream_t st, const float* W, int K, int N, int KC, u16* Op)
{
    dim3 g(N / 64, KC / 8), b(256);
    split_b<<<g, b, 0, st>>>(W, K, N, KC, Op);
}

extern "C" void kernel_launch(void* const* d_in, const int* in_sizes, int n_in,
                              void* d_out, int out_size, void* d_ws, size_t ws_size,
                              hipStream_t stream)
{
    const float* obj_embs  = (const float*)d_in[0];
    const float* pred_embs = (const float*)d_in[2];
    const int*   rels      = (const int*)d_in[4];
    const int*   objs      = (const int*)d_in[5];
    const float* obj_table = (const float*)d_in[6];
    const float* rel_table = (const float*)d_in[7];
    const float* Wf_obj = (const float*)d_in[8];
    const float* bf_obj = (const float*)d_in[9];
    const float* Wf_rel = (const float*)d_in[10];
    const float* bf_rel = (const float*)d_in[11];
    const float* W1a = (const float*)d_in[12];
    const float* b1a = (const float*)d_in[13];
    const float* W1b = (const float*)d_in[14];
    const float* b1b = (const float*)d_in[15];
    const float* W2a = (const float*)d_in[16];
    const float* b2a = (const float*)d_in[17];
    const float* W2b = (const float*)d_in[18];
    const float* b2b = (const float*)d_in[19];
    const float* Ws1a = (const float*)d_in[20];
    const float* bs1a = (const float*)d_in[21];
    const float* Ws1b = (const float*)d_in[22];
    const float* bs1b = (const float*)d_in[23];
    const float* Ws2a = (const float*)d_in[24];
    const float* bs2a = (const float*)d_in[25];
    const float* Ws2b = (const float*)d_in[26];
    const float* bs2b = (const float*)d_in[27];
    float* out = (float*)d_out;

    // ---- workspace layout (bytes), total ~119.6 MB ----
    unsigned char* B8 = (unsigned char*)d_ws;
    constexpr size_t S1O  = 0;                     // concat-A planes    29,097,984
    constexpr size_t S2O  = 29097984;              // chunk-out planes   25,165,824
    constexpr size_t S3AO = 54263808;              // Wf B planes        29,097,984
    constexpr size_t ZSZ  = 86507520;              // overlay-zone size
    //   overlays inside zone (live only after L0's PP GEMM):
    constexpr size_t T2O  = 0;                     // 36,864,000
    constexpr size_t TTO  = 36864000;              // 18,481,152 (TTp / Hp)
    constexpr size_t PVO  = 55345152;              // 18,481,152 (PVpS)
    constexpr size_t PLO  = 73826304;              //  6,291,456 (PLp)
    constexpr size_t OVO  = 80117760;              //  6,291,456 (OVpS)
    constexpr size_t S3BO = ZSZ;                   //  6,291,456 (B slot b)
    constexpr size_t S3CO = S3BO + 6291456;        //  6,291,456 (B slot c)
    constexpr size_t PPO  = S3CO + 6291456;        // 12,288,000
    constexpr size_t P1O  = PPO + 12288000;        //  4,096,000 (also PO)
    constexpr size_t P2O  = P1O + 4096000;         //  4,096,000
    constexpr size_t CNO  = P2O + 4096000;         //  8,000

    u16* S1  = (u16*)(B8 + S1O);
    u16* S2  = (u16*)(B8 + S2O);
    u16* S3A = (u16*)(B8 + S3AO);
    u16* S3B = (u16*)(B8 + S3BO);
    u16* S3C = (u16*)(B8 + S3CO);
    float* T2 = (float*)(B8 + T2O);
    u16* TTp  = (u16*)(B8 + TTO);
    u16* Hp   = (u16*)(B8 + TTO);                 // overlays TTp (disjoint in time)
    u16* PVp  = (u16*)(B8 + PVO);
    u16* PLp  = (u16*)(B8 + PLO);
    u16* OVp  = (u16*)(B8 + OVO);
    float* PP = (float*)(B8 + PPO);
    float* P1 = (float*)(B8 + P1O);
    float* P2 = (float*)(B8 + P2O);
    float* PO = P1;                                // reuse (P1 dead after edge)
    int* CNT  = (int*)(B8 + CNO);

    // ---- edge counts (fixed for whole call) ----
    hipMemsetAsync(CNT, 0, O_N * sizeof(int), stream);
    hipLaunchKernelGGL(count_edges, dim3((T_N + 255) / 256), dim3(256), 0, stream, rels, CNT);

    // ================= projections + layer-0 front =================
    // obj: OV-chunk planes -> P1/P2 via W1a top/bot
    SB(stream, Wf_obj, DIN + DW, DIN, 296, S3A);
    {
        dim3 g(8, 296), b(256);
        split_concat_a<<<g, b, 0, stream>>>(obj_embs, DIN, DIN, obj_table, DW,
                                            objs, 1, 0, O_N, 2048, 296, S1);
    }
    // in-block K-split 128x128: grid 256 @ 512 thr
    GK2<128, 128>(stream, S1, 2048, S3A, DIN, 296, O_N, bf_obj, 1,
                  nullptr, 0, S2, 2048);
    SB(stream, W1a, DIN, HH_, 256, S3B);                       // top (L0 K=2048)
    SB(stream, W1a + (size_t)2 * DIN * HH_, DIN, HH_, 256, S3C); // bot
    GX<64, 64>(stream, S2, 2048, S3B, HH_, 256, O_N, nullptr, 0,
               P1, HH_, nullptr, 0, S3C, P2, nullptr);
    // pred, M-chunked: proj -> PV-chunk planes -> PP via W1a mid
    SB(stream, Wf_rel, DIN + DW, DIN, 296, S3A);
    SB(stream, W1a + (size_t)DIN * HH_, DIN, HH_, 256, S3B);   // mid
    for (int ch = 0; ch < 3; ch++) {
        int ch0 = ch * 2048;
        int mp  = (ch == 2) ? 1920 : 2048;
        int mv  = (ch == 2) ? 1904 : 2048;
        dim3 g((mp + 255) / 256, 296), b(256);
        split_concat_a<<<g, b, 0, stream>>>(pred_embs, DIN, DIN, rel_table, DW,
                                            rels + 1, 3, ch0, T_N, mp, 296, S1);
        GK2<128, 128>(stream, S1, mp, S3A, DIN, 296, mv, bf_rel, 1,
                      nullptr, 0, S2, mp);
        GX<64, 64>(stream, S2, mp, S3B, HH_, 256, mv, nullptr, 0,
                   PP + (size_t)ch0 * HH_, HH_, nullptr, 0,
                   nullptr, nullptr, nullptr);
    }

    // ================= 5 conv layers =================
    for (int L = 0; L < 5; L++) {
        const float* bb1a = (L == 0) ? b1a : (bs1a + (size_t)(L - 1) * HH_);
        const float* w1b  = (L == 0) ? W1b : (Ws1b + (size_t)(L - 1) * HH_ * 1536);
        const float* bb1b = (L == 0) ? b1b : (bs1b + (size_t)(L - 1) * 1536);
        const float* w2a  = (L == 0) ? W2a : (Ws2a + (size_t)(L - 1) * HH_ * HH_);
        const float* bb2a = (L == 0) ? b2a : (bs2a + (size_t)(L - 1) * HH_);
        const float* w2b  = (L == 0) ? W2b : (Ws2b + (size_t)(L - 1) * HH_ * DG);
        const float* bb2b = (L == 0) ? b2b : (bs2b + (size_t)(L - 1) * DG);

        if (L > 0) {
            const float* w1a = Ws1a + (size_t)(L - 1) * 3 * HH_ * HH_;
            SB(stream, w1a, HH_, HH_, 64, S3B);                       // top
            SB(stream, w1a + (size_t)2 * HH_ * HH_, HH_, HH_, 64, S3C); // bot
            GX<64, 64>(stream, OVp, 2048, S3B, HH_, 64, O_N, nullptr, 0,
                       P1, HH_, nullptr, 0, S3C, P2, nullptr);
            SB(stream, w1a + (size_t)HH_ * HH_, HH_, HH_, 64, S3B);   // mid
            GX<64, 64>(stream, PVp, 6016, S3B, HH_, 64, T_N, nullptr, 0,
                       PP, HH_, nullptr, 0, nullptr, nullptr, nullptr);
        }

        // edge combine -> TT planes
        {
            dim3 g(24, 64), b(256);
            edge_planes<<<g, b, 0, stream>>>(PP, P1, P2, rels, bb1a, 6016, TTp);
        }
        // t2 = relu(TT @ W1b + b1b) — 564 blocks, 3 resident/CU, best LDS/flop
        SB(stream, w1b, HH_, 1536, 64, S3C);
        GX<128, 128>(stream, TTp, 6016, S3C, 1536, 64, T_N, bb1b, 1,
                     T2, 1536, nullptr, 0, nullptr, nullptr, nullptr);
        // pooling
        hipMemsetAsync(PO, 0, (size_t)O_N * HH_ * sizeof(float), stream);
        hipLaunchKernelGGL(scatter_pool, dim3(T_N), dim3(256), 0, stream, T2, rels, PO);
        {
            dim3 g(8, 64), b(256);
            pool_planes<<<g, b, 0, stream>>>(PO, CNT, 2048, PLp);
        }
        // obj MLP2
        SB(stream, w2a, HH_, HH_, 64, S3B);
        GX<64, 64>(stream, PLp, 2048, S3B, HH_, 64, O_N, bb2a, 1,
                   nullptr, 0, Hp, 2048, nullptr, nullptr, nullptr);
        SB(stream, w2b, HH_, DG, 64, S3C);
        if (L < 4) {
            GX<64, 64>(stream, Hp, 2048, S3C, DG, 64, O_N, bb2b, 1,
                       nullptr, 0, OVp, 2048, nullptr, nullptr, nullptr);
            dim3 g(24, 64), b(256);
            predcopy_planes<<<g, b, 0, stream>>>(T2, 6016, PVp);
        } else {
            GX<64, 64>(stream, Hp, 2048, S3C, DG, 64, O_N, bb2b, 1,
                       out, DG, nullptr, 0, nullptr, nullptr, nullptr);
            hipLaunchKernelGGL(predcopy_f32, dim3((T_N * HH_ / 4 + 255) / 256),
                               dim3(256), 0, stream, T2, out + (size_t)O_N * DG);
        }
    }
}

// Round 5
// 1772.331 us; speedup vs baseline: 1.5911x; 1.1349x over previous
//
#include <hip/hip_runtime.h>

#define O_N 2000
#define T_N 6000
#define DIN 2048
#define DW  300
#define DG  512
#define HH_ 512

typedef __attribute__((ext_vector_type(8)))  short short8;
typedef __attribute__((ext_vector_type(16))) float f32x16;
typedef unsigned short u16;

__device__ __forceinline__ float4 ld4(const float* p) { return *(const float4*)p; }

// ---- bf16 split-3 helpers (RNE) ----
__device__ __forceinline__ u16 rbf(float x) {
    unsigned int u = __float_as_uint(x);
    u += 0x7FFFu + ((u >> 16) & 1u);
    return (u16)(u >> 16);
}
__device__ __forceinline__ float fbf(u16 h) {
    return __uint_as_float((unsigned int)h << 16);
}
__device__ __forceinline__ void split3(float x, short& h, short& m, short& l) {
    u16 a = rbf(x);
    float r = x - fbf(a);
    u16 b = rbf(r);
    r -= fbf(b);
    u16 c = rbf(r);
    h = (short)a; m = (short)b; l = (short)c;
}

// ---- async global->LDS, 16B per lane (wave-uniform LDS base) ----
__device__ __forceinline__ void gl_lds16(u16* lds, const u16* g) {
    auto* gp = (const __attribute__((address_space(1))) unsigned int*)g;
    auto* lp = (__attribute__((address_space(3))) unsigned int*)lds;
    __builtin_amdgcn_global_load_lds(gp, lp, 16, 0, 0);
}

// =====================================================================
// MFMA GEMM: C = act(A @ B + bias) with A,B given as 3 bf16 planes
// (hi/mid/lo), chunk-major layout [K/8][Mp][8] (A) / [K/8][N][8] (B).
// 6 MFMA products: hh -> acc_hi ; hm, mh, hl, mm, lh -> acc_lo.
// KS=0: 256 thr = 4 waves (2x2).  KS=1: 512 thr = 8 waves = 2 K-groups.
//
// K-loop schedule (T3/T4, counted vmcnt): TRIPLE-buffered LDS, 2-deep
// global_load_lds prefetch. Per iteration:
//   stage tile t+2 -> buf[(t+2)%3]
//   s_waitcnt vmcnt(2*LDMIN)          // tile t landed; t+1,t+2 in flight
//   s_barrier                          // fill barrier
//   ds_read all A/B fragments of buf[t%3]
//   s_waitcnt lgkmcnt(0)               // reads returned -> buffer free
//   s_barrier                          // consume barrier
//   24 MFMA (register-only; executes under next iter's stage/reads)
// vmcnt never drains to 0 in the loop -> no per-iteration HBM-latency
// exposure. Consume barrier is preceded by lgkm drain, so re-staging a
// buffer (one full iteration later) cannot race the reads. All waves
// execute identical barrier counts. Numerics identical (same MFMA order).
// =====================================================================
template<int BM, int BN, int KS>
__global__ __launch_bounds__(KS ? 512 : 256, KS ? 2 : (BM == 64 ? 4 : 2))
void gemm_mx(
    const u16* __restrict__ Ap, int MpA,
    const u16* __restrict__ Bp, int N, int KC, int M,
    const float* __restrict__ bias, int doRelu,
    float* __restrict__ C, int ldc,
    u16* __restrict__ Op, int MpO,
    const u16* __restrict__ Bp2, float* __restrict__ C2, u16* __restrict__ Op2,
    int nbx)
{
    static_assert(BM == 128 || BM == 64, "BM in {64,128}");
    constexpr int WM = BM / 2, WN = BN / 2;
    constexpr int FI = WM / 32, FJ = WN / 32;
    static_assert(!KS || FI == 2, "KS path needs FI=2");
    constexpr int UA = 6 * BM;            // 16B staging units per tile (A)
    constexpr int UB = 6 * BN;
    constexpr int NI = (UA + UB) / 64;    // staging instructions per tile
    constexpr int II = (NI + 3) / 4;      // per wave (4 waves per group)
    constexpr int LDMIN = NI / 4;         // min loads/wave (vmcnt-safe floor)
    constexpr int BUF = (BM + BN) * 48;   // ushorts per LDS buffer
    __shared__ u16 sm[(KS ? 6 : 3) * BUF];

    const int tid = threadIdx.x;
    const int w = tid >> 6, lane = tid & 63;
    const int wg = w & 3;                 // wave-in-group (== w when KS=0)
    const int g = KS ? (w >> 2) : 0;      // K-group
    const int ln31 = lane & 31, lq = lane >> 5;

    int bx = blockIdx.x;
    const u16* Bpl = Bp; float* Cl = C; u16* Opl = Op;
    if (bx >= nbx) { bx -= nbx; Bpl = Bp2; Cl = C2; Opl = Op2; }
    const int n0 = bx * BN, m0 = blockIdx.y * BM;
    const long psA = (long)KC * MpA * 8;  // full plane strides
    const long psB = (long)KC * N * 8;

    int c0 = 0, cn = KC;
    if (KS) { int h = (KC >> 2) << 1; c0 = g ? h : 0; cn = g ? (KC - h) : h; }
    const u16* ApG = Ap + (long)c0 * MpA * 8;
    const u16* BpG = Bpl + (long)c0 * N * 8;
    u16* smg = sm + g * 3 * BUF;

    // ---- staging assignment (per-wave instructions, 64 rows x 16B each) ----
    const u16* gb[II]; int gstep[II]; int lob[II]; bool gv[II];
#pragma unroll
    for (int ii = 0; ii < II; ii++) {
        int n = wg + 4 * ii;
        gv[ii] = n < NI;
        int nn = gv[ii] ? n : 0;
        int u0 = nn * 64;
        bool isA = u0 < UA;
        int uu = isA ? u0 : u0 - UA;
        int dim = isA ? BM : BN;
        int row0 = uu % dim, pq = uu / dim;
        int q = pq & 1, p = pq >> 1;
        const u16* pb = (isA ? ApG : BpG) + (long)p * (isA ? psA : psB);
        int mp = isA ? MpA : N;
        gb[ii] = pb + ((long)q * mp + (isA ? m0 : n0) + row0 + lane) * 8;
        gstep[ii] = mp * 16;              // ushorts per tile (2 chunks)
        lob[ii] = (isA ? (pq * BM + row0) : (6 * BM + pq * BN + row0)) * 8;
    }

    f32x16 ah[FI][FJ], al[FI][FJ];
#pragma unroll
    for (int fi = 0; fi < FI; fi++)
#pragma unroll
        for (int fj = 0; fj < FJ; fj++)
#pragma unroll
            for (int r = 0; r < 16; r++) { ah[fi][fj][r] = 0.f; al[fi][fj][r] = 0.f; }

    const int T = cn >> 1;
    // ---- prologue: stage tiles 0 and 1 (2-deep) ----
#pragma unroll
    for (int ii = 0; ii < II; ii++)
        if (gv[ii]) { gl_lds16(smg + lob[ii], gb[ii]); }
    if (T > 1) {
#pragma unroll
        for (int ii = 0; ii < II; ii++)
            if (gv[ii]) gl_lds16(smg + BUF + lob[ii], gb[ii] + (long)gstep[ii]);
    }
#pragma unroll
    for (int ii = 0; ii < II; ii++) gb[ii] += (long)2 * gstep[ii];

    int cb = 0, sb = 2 * BUF;             // read offset / stage-dest offset
    for (int t = 0; t < T; t++) {
        if (t + 2 < T) {
#pragma unroll
            for (int ii = 0; ii < II; ii++)
                if (gv[ii]) gl_lds16(smg + sb + lob[ii], gb[ii]);
#pragma unroll
            for (int ii = 0; ii < II; ii++) gb[ii] += (long)gstep[ii];
        }
        // wait for tile t's loads only; keep t+1/t+2 in flight
        if (t + 2 < T)      asm volatile("s_waitcnt vmcnt(%0)" :: "i"(2 * LDMIN) : "memory");
        else if (t + 1 < T) asm volatile("s_waitcnt vmcnt(%0)" :: "i"(LDMIN) : "memory");
        else                asm volatile("s_waitcnt vmcnt(0)" ::: "memory");
        __builtin_amdgcn_s_barrier();                       // fill barrier
        asm volatile("" ::: "memory");

        const u16* ab = smg + cb;
        const u16* bb = ab + 6 * BM * 8;
        short8 af[FI][3], bf[FJ][3];
#pragma unroll
        for (int fi = 0; fi < FI; fi++)
#pragma unroll
            for (int p = 0; p < 3; p++)
                af[fi][p] = *(const short8*)(ab + ((p * 2 + lq) * BM + (wg >> 1) * WM + fi * 32 + ln31) * 8);
#pragma unroll
        for (int fj = 0; fj < FJ; fj++) {
            const int rB = (wg & 1) * WN + fj * 32 + ln31;
#pragma unroll
            for (int p = 0; p < 3; p++)
                bf[fj][p] = *(const short8*)(bb + ((p * 2 + lq) * BN + rB) * 8);
        }
        asm volatile("s_waitcnt lgkmcnt(0)" ::: "memory");  // reads returned
        __builtin_amdgcn_s_barrier();                       // consume barrier
        asm volatile("" ::: "memory");

#pragma unroll
        for (int fj = 0; fj < FJ; fj++) {
#pragma unroll
            for (int fi = 0; fi < FI; fi++) {
                ah[fi][fj] = __builtin_amdgcn_mfma_f32_32x32x16_bf16(af[fi][0], bf[fj][0], ah[fi][fj], 0, 0, 0);
                al[fi][fj] = __builtin_amdgcn_mfma_f32_32x32x16_bf16(af[fi][0], bf[fj][1], al[fi][fj], 0, 0, 0);
                al[fi][fj] = __builtin_amdgcn_mfma_f32_32x32x16_bf16(af[fi][1], bf[fj][0], al[fi][fj], 0, 0, 0);
                al[fi][fj] = __builtin_amdgcn_mfma_f32_32x32x16_bf16(af[fi][0], bf[fj][2], al[fi][fj], 0, 0, 0);
                al[fi][fj] = __builtin_amdgcn_mfma_f32_32x32x16_bf16(af[fi][1], bf[fj][1], al[fi][fj], 0, 0, 0);
                al[fi][fj] = __builtin_amdgcn_mfma_f32_32x32x16_bf16(af[fi][2], bf[fj][0], al[fi][fj], 0, 0, 0);
            }
        }
        cb += BUF; if (cb == 3 * BUF) cb = 0;
        sb += BUF; if (sb == 3 * BUF) sb = 0;
    }

    // ---- KS partial exchange: group g exports fi=(1-g), keeps fi=g ----
    // All register indexing is static inside wave-uniform branches (rule #20).
    float tv[FJ][16];
    if (KS) {
        constexpr int XW = FJ * 16 * 64;                 // floats per wave export
        float* xs = (float*)sm;
        float* wrp = xs + (1 - g) * 4 * XW + wg * XW;    // region for fi=(1-g)
        if (g == 0) {
#pragma unroll
            for (int fj = 0; fj < FJ; fj++)
#pragma unroll
                for (int r = 0; r < 16; r++)
                    wrp[(fj * 16 + r) * 64 + lane] = ah[1][fj][r] + al[1][fj][r];
        } else {
#pragma unroll
            for (int fj = 0; fj < FJ; fj++)
#pragma unroll
                for (int r = 0; r < 16; r++)
                    wrp[(fj * 16 + r) * 64 + lane] = ah[0][fj][r] + al[0][fj][r];
        }
        __syncthreads();
        float* rdp = xs + g * 4 * XW + wg * XW;          // partner's export of fi=g
        if (g == 0) {
#pragma unroll
            for (int fj = 0; fj < FJ; fj++)
#pragma unroll
                for (int r = 0; r < 16; r++)
                    tv[fj][r] = ah[0][fj][r] + al[0][fj][r] + rdp[(fj * 16 + r) * 64 + lane];
        } else {
#pragma unroll
            for (int fj = 0; fj < FJ; fj++)
#pragma unroll
                for (int r = 0; r < 16; r++)
                    tv[fj][r] = ah[1][fj][r] + al[1][fj][r] + rdp[(fj * 16 + r) * 64 + lane];
        }
        __syncthreads();   // exchange fully read before bounce reuses sm
    }

    // ---- epilogue (KS: wave writes only its fi==g half; 8 waves x 2 tiles) ----
    float* bounce = (float*)sm + w * 1184;     // 32x36 floats, per-wave region
    const long psO = (long)N * MpO;            // ushorts per out plane
#pragma unroll
    for (int fi = 0; fi < FI; fi++) {
        if (KS && fi != g) continue;
#pragma unroll
        for (int fj = 0; fj < FJ; fj++) {
            const int colBase = n0 + (wg & 1) * WN + fj * 32;
            const int rowBase = m0 + (wg >> 1) * WM + fi * 32;
            float bv = bias ? bias[colBase + ln31] : 0.f;
            float v[16];
#pragma unroll
            for (int r = 0; r < 16; r++) {
                float s = KS ? tv[fj][r] : (ah[fi][fj][r] + al[fi][fj][r]);
                float x = s + bv;
                if (doRelu) x = fmaxf(x, 0.f);
                v[r] = x;
            }
            if (Cl) {
#pragma unroll
                for (int r = 0; r < 16; r++) {
                    int row = rowBase + (r & 3) + 8 * (r >> 2) + 4 * lq;
                    if (row < M)
                        Cl[(long)row * ldc + colBase + ln31] = v[r];
                }
            }
            if (Opl) {
#pragma unroll
                for (int r = 0; r < 16; r++)
                    bounce[((r & 3) + 8 * (r >> 2) + 4 * lq) * 36 + ln31] = v[r];
#pragma unroll
                for (int u = 0; u < 2; u++) {
                    int urow = ln31, uc = lq + 2 * u;
                    const float* rp = bounce + urow * 36 + uc * 8;
                    short8 h8, m8, l8;
#pragma unroll
                    for (int j = 0; j < 8; j++) {
                        short a, b, c2; split3(rp[j], a, b, c2);
                        h8[j] = a; m8[j] = b; l8[j] = c2;
                    }
                    long cIdx = (long)((colBase + uc * 8) >> 3);
                    long base = (cIdx * MpO + rowBase + urow) * 8;
                    *(short8*)(Opl + base) = h8;
                    *(short8*)(Opl + psO + base) = m8;
                    *(short8*)(Opl + 2 * psO + base) = l8;
                }
            }
        }
    }
}

// ---- split weights: W [K][N] fp32 -> 3 planes [K/8][N][8] bf16 ----
__global__ __launch_bounds__(256) void split_b(
    const float* __restrict__ W, int K, int N, int KC,
    u16* __restrict__ Op)
{
    __shared__ float tl[64][65];
    const int tid = threadIdx.x;
    const int n0 = blockIdx.x * 64, k0 = blockIdx.y * 64;
    const long ps = (long)KC * N * 8;
#pragma unroll
    for (int l = 0; l < 4; l++) {
        int k = (tid >> 4) + l * 16;
        int nn = (tid & 15) << 2;
        float4 v = make_float4(0.f, 0.f, 0.f, 0.f);
        if (k0 + k < K) v = ld4(W + (long)(k0 + k) * N + n0 + nn);
        tl[k][nn] = v.x; tl[k][nn + 1] = v.y; tl[k][nn + 2] = v.z; tl[k][nn + 3] = v.w;
    }
    __syncthreads();
#pragma unroll
    for (int l = 0; l < 2; l++) {
        int u = tid + l * 256;
        int n = u & 63, c = u >> 6;
        short8 h8, m8, l8;
#pragma unroll
        for (int j = 0; j < 8; j++) {
            short a, b, c2; split3(tl[c * 8 + j][n], a, b, c2);
            h8[j] = a; m8[j] = b; l8[j] = c2;
        }
        long base = ((long)(k0 / 8 + c) * N + n0 + n) * 8;
        *(short8*)(Op + base) = h8;
        *(short8*)(Op + ps + base) = m8;
        *(short8*)(Op + 2 * ps + base) = l8;
    }
}

__device__ __forceinline__ void store_planes(u16* Op, long ps, long base, const float* x)
{
    short8 h8, m8, l8;
#pragma unroll
    for (int j = 0; j < 8; j++) {
        short a, b, c2; split3(x[j], a, b, c2);
        h8[j] = a; m8[j] = b; l8[j] = c2;
    }
    *(short8*)(Op + base) = h8;
    *(short8*)(Op + ps + base) = m8;
    *(short8*)(Op + 2 * ps + base) = l8;
}

// ---- concat(A | Tab[idx]) fp32 -> planes [KC][Mp][8] ----
__global__ __launch_bounds__(256) void split_concat_a(
    const float* __restrict__ E, int ldE, int KA,
    const float* __restrict__ Tab, int DWc,
    const int* __restrict__ idx, int idxStride,
    int mBase, int Mvalid, int Mp, int KC,
    u16* __restrict__ Op)
{
    int m = blockIdx.x * 256 + threadIdx.x;
    if (m >= Mp) return;
    int c = blockIdx.y;
    int gm = mBase + m;
    float x[8];
    if (gm >= Mvalid) {
#pragma unroll
        for (int j = 0; j < 8; j++) x[j] = 0.f;
    } else {
        int k0 = c * 8;
        if (k0 + 8 <= KA) {
            float4 a = ld4(E + (long)gm * ldE + k0);
            float4 b = ld4(E + (long)gm * ldE + k0 + 4);
            x[0] = a.x; x[1] = a.y; x[2] = a.z; x[3] = a.w;
            x[4] = b.x; x[5] = b.y; x[6] = b.z; x[7] = b.w;
        } else {
            const float* tr = Tab + (long)idx[(long)gm * idxStride] * DWc;
#pragma unroll
            for (int j = 0; j < 8; j++) {
                int k = k0 + j;
                x[j] = (k < KA) ? E[(long)gm * ldE + k]
                                : ((k - KA) < DWc ? tr[k - KA] : 0.f);
            }
        }
    }
    store_planes(Op, (long)KC * Mp * 8, ((long)c * Mp + m) * 8, x);
}

// ---- edge combine: relu(P1[s]+PP+P2[o]+b1a) -> planes (KC=64) ----
__global__ __launch_bounds__(256) void edge_planes(
    const float* __restrict__ PPv, const float* __restrict__ P1v,
    const float* __restrict__ P2v, const int* __restrict__ rels,
    const float* __restrict__ b1a, int Mp, u16* __restrict__ Op)
{
    int m = blockIdx.x * 256 + threadIdx.x;
    if (m >= Mp) return;
    int c = blockIdx.y;
    float x[8];
    if (m >= T_N) {
#pragma unroll
        for (int j = 0; j < 8; j++) x[j] = 0.f;
    } else {
        int s = rels[3 * m], o = rels[3 * m + 2];
        const float* pp = PPv + (long)m * HH_ + c * 8;
        const float* p1 = P1v + (long)s * HH_ + c * 8;
        const float* p2 = P2v + (long)o * HH_ + c * 8;
        const float* bb = b1a + c * 8;
#pragma unroll
        for (int j = 0; j < 8; j++)
            x[j] = fmaxf(pp[j] + p1[j] + p2[j] + bb[j], 0.f);
    }
    store_planes(Op, (long)64 * Mp * 8, ((long)c * Mp + m) * 8, x);
}

// ---- pooled/cnt -> planes (KC=64) ----
__global__ __launch_bounds__(256) void pool_planes(
    const float* __restrict__ PO, const int* __restrict__ CNT,
    int Mp, u16* __restrict__ Op)
{
    int m = blockIdx.x * 256 + threadIdx.x;
    if (m >= Mp) return;
    int c = blockIdx.y;
    float x[8];
    if (m >= O_N) {
#pragma unroll
        for (int j = 0; j < 8; j++) x[j] = 0.f;
    } else {
        int cc = CNT[m]; float cf = 1.f / (float)(cc < 1 ? 1 : cc);
#pragma unroll
        for (int j = 0; j < 8; j++) x[j] = PO[(long)m * HH_ + c * 8 + j] * cf;
    }
    store_planes(Op, (long)64 * Mp * 8, ((long)c * Mp + m) * 8, x);
}

// ---- T2 mid slice -> PV planes (KC=64) ----
__global__ __launch_bounds__(256) void predcopy_planes(
    const float* __restrict__ T2, int Mp, u16* __restrict__ Op)
{
    int m = blockIdx.x * 256 + threadIdx.x;
    if (m >= Mp) return;
    int c = blockIdx.y;
    float x[8];
    if (m >= T_N) {
#pragma unroll
        for (int j = 0; j < 8; j++) x[j] = 0.f;
    } else {
#pragma unroll
        for (int j = 0; j < 8; j++) x[j] = T2[(long)m * 1536 + 512 + c * 8 + j];
    }
    store_planes(Op, (long)64 * Mp * 8, ((long)c * Mp + m) * 8, x);
}

__global__ void predcopy_f32(const float* __restrict__ T2, float* __restrict__ dst)
{
    int i = blockIdx.x * 256 + threadIdx.x;   // float4 index
    if (i >= T_N * HH_ / 4) return;
    int e = i / (HH_ / 4);
    int j = (i % (HH_ / 4)) << 2;
    float4 v = ld4(T2 + (long)e * 1536 + 512 + j);
    *(float4*)(dst + (long)e * HH_ + j) = v;
}

__global__ void count_edges(const int* __restrict__ rels, int* __restrict__ CNT)
{
    int e = blockIdx.x * 256 + threadIdx.x;
    if (e >= T_N) return;
    atomicAdd(CNT + rels[3 * e + 0], 1);
    atomicAdd(CNT + rels[3 * e + 2], 1);
}

__global__ void scatter_pool(const float* __restrict__ T2,
                             const int* __restrict__ rels,
                             float* __restrict__ PO)
{
    int e = blockIdx.x;
    int t = threadIdx.x;            // 256
    int s = rels[e * 3 + 0];
    int o = rels[e * 3 + 2];
#pragma unroll
    for (int u = 0; u < 2; u++) {
        int j = t + u * 256;
        unsafeAtomicAdd(PO + (long)s * HH_ + j, T2[(long)e * 1536 + j]);
        unsafeAtomicAdd(PO + (long)o * HH_ + j, T2[(long)e * 1536 + 1024 + j]);
    }
}

// ---- host-side helpers ----
template<int BM, int BN>
static inline void GX(hipStream_t st, const u16* Ap, int MpA,
                      const u16* Bp, int N, int KC, int M,
                      const float* bias, int relu_,
                      float* C, int ldc, u16* Op, int MpO,
                      const u16* Bp2, float* C2, u16* Op2)
{
    int nbx = N / BN;
    int pair = (Bp2 != nullptr) ? 2 : 1;
    dim3 g(nbx * pair, MpA / BM), b(256);
    gemm_mx<BM, BN, 0><<<g, b, 0, st>>>(Ap, MpA, Bp, N, KC, M, bias, relu_,
                                        C, ldc, Op, MpO, Bp2, C2, Op2, nbx);
}

// in-block K-split launch (512 threads, KC%4==0 required)
template<int BM, int BN>
static inline void GK2(hipStream_t st, const u16* Ap, int MpA,
                       const u16* Bp, int N, int KC, int M,
                       const float* bias, int relu_,
                       float* C, int ldc, u16* Op, int MpO)
{
    dim3 g(N / BN, MpA / BM), b(512);
    gemm_mx<BM, BN, 1><<<g, b, 0, st>>>(Ap, MpA, Bp, N, KC, M, bias, relu_,
                                        C, ldc, Op, MpO,
                                        nullptr, nullptr, nullptr, N / BN);
}

static inline void SB(hipStream_t st, const float* W, int K, int N, int KC, u16* Op)
{
    dim3 g(N / 64, KC / 8), b(256);
    split_b<<<g, b, 0, st>>>(W, K, N, KC, Op);
}

extern "C" void kernel_launch(void* const* d_in, const int* in_sizes, int n_in,
                              void* d_out, int out_size, void* d_ws, size_t ws_size,
                              hipStream_t stream)
{
    const float* obj_embs  = (const float*)d_in[0];
    const float* pred_embs = (const float*)d_in[2];
    const int*   rels      = (const int*)d_in[4];
    const int*   objs      = (const int*)d_in[5];
    const float* obj_table = (const float*)d_in[6];
    const float* rel_table = (const float*)d_in[7];
    const float* Wf_obj = (const float*)d_in[8];
    const float* bf_obj = (const float*)d_in[9];
    const float* Wf_rel = (const float*)d_in[10];
    const float* bf_rel = (const float*)d_in[11];
    const float* W1a = (const float*)d_in[12];
    const float* b1a = (const float*)d_in[13];
    const float* W1b = (const float*)d_in[14];
    const float* b1b = (const float*)d_in[15];
    const float* W2a = (const float*)d_in[16];
    const float* b2a = (const float*)d_in[17];
    const float* W2b = (const float*)d_in[18];
    const float* b2b = (const float*)d_in[19];
    const float* Ws1a = (const float*)d_in[20];
    const float* bs1a = (const float*)d_in[21];
    const float* Ws1b = (const float*)d_in[22];
    const float* bs1b = (const float*)d_in[23];
    const float* Ws2a = (const float*)d_in[24];
    const float* bs2a = (const float*)d_in[25];
    const float* Ws2b = (const float*)d_in[26];
    const float* bs2b = (const float*)d_in[27];
    float* out = (float*)d_out;

    // ---- workspace layout (bytes), total ~119.6 MB ----
    unsigned char* B8 = (unsigned char*)d_ws;
    constexpr size_t S1O  = 0;                     // concat-A planes    29,097,984
    constexpr size_t S2O  = 29097984;              // chunk-out planes   25,165,824
    constexpr size_t S3AO = 54263808;              // Wf B planes        29,097,984
    constexpr size_t ZSZ  = 86507520;              // overlay-zone size
    //   overlays inside zone (live only after L0's PP GEMM):
    constexpr size_t T2O  = 0;                     // 36,864,000
    constexpr size_t TTO  = 36864000;              // 18,481,152 (TTp / Hp)
    constexpr size_t PVO  = 55345152;              // 18,481,152 (PVpS)
    constexpr size_t PLO  = 73826304;              //  6,291,456 (PLp)
    constexpr size_t OVO  = 80117760;              //  6,291,456 (OVpS)
    constexpr size_t S3BO = ZSZ;                   //  6,291,456 (B slot b)
    constexpr size_t S3CO = S3BO + 6291456;        //  6,291,456 (B slot c)
    constexpr size_t PPO  = S3CO + 6291456;        // 12,288,000
    constexpr size_t P1O  = PPO + 12288000;        //  4,096,000 (also PO)
    constexpr size_t P2O  = P1O + 4096000;         //  4,096,000
    constexpr size_t CNO  = P2O + 4096000;         //  8,000

    u16* S1  = (u16*)(B8 + S1O);
    u16* S2  = (u16*)(B8 + S2O);
    u16* S3A = (u16*)(B8 + S3AO);
    u16* S3B = (u16*)(B8 + S3BO);
    u16* S3C = (u16*)(B8 + S3CO);
    float* T2 = (float*)(B8 + T2O);
    u16* TTp  = (u16*)(B8 + TTO);
    u16* Hp   = (u16*)(B8 + TTO);                 // overlays TTp (disjoint in time)
    u16* PVp  = (u16*)(B8 + PVO);
    u16* PLp  = (u16*)(B8 + PLO);
    u16* OVp  = (u16*)(B8 + OVO);
    float* PP = (float*)(B8 + PPO);
    float* P1 = (float*)(B8 + P1O);
    float* P2 = (float*)(B8 + P2O);
    float* PO = P1;                                // reuse (P1 dead after edge)
    int* CNT  = (int*)(B8 + CNO);

    // ---- edge counts (fixed for whole call) ----
    hipMemsetAsync(CNT, 0, O_N * sizeof(int), stream);
    hipLaunchKernelGGL(count_edges, dim3((T_N + 255) / 256), dim3(256), 0, stream, rels, CNT);

    // ================= projections + layer-0 front =================
    // obj: OV-chunk planes -> P1/P2 via W1a top/bot
    SB(stream, Wf_obj, DIN + DW, DIN, 296, S3A);
    {
        dim3 g(8, 296), b(256);
        split_concat_a<<<g, b, 0, stream>>>(obj_embs, DIN, DIN, obj_table, DW,
                                            objs, 1, 0, O_N, 2048, 296, S1);
    }
    // in-block K-split 128x128: grid 256 @ 512 thr
    GK2<128, 128>(stream, S1, 2048, S3A, DIN, 296, O_N, bf_obj, 1,
                  nullptr, 0, S2, 2048);
    SB(stream, W1a, DIN, HH_, 256, S3B);                       // top (L0 K=2048)
    SB(stream, W1a + (size_t)2 * DIN * HH_, DIN, HH_, 256, S3C); // bot
    GX<64, 64>(stream, S2, 2048, S3B, HH_, 256, O_N, nullptr, 0,
               P1, HH_, nullptr, 0, S3C, P2, nullptr);
    // pred, M-chunked: proj -> PV-chunk planes -> PP via W1a mid
    SB(stream, Wf_rel, DIN + DW, DIN, 296, S3A);
    SB(stream, W1a + (size_t)DIN * HH_, DIN, HH_, 256, S3B);   // mid
    for (int ch = 0; ch < 3; ch++) {
        int ch0 = ch * 2048;
        int mp  = (ch == 2) ? 1920 : 2048;
        int mv  = (ch == 2) ? 1904 : 2048;
        dim3 g((mp + 255) / 256, 296), b(256);
        split_concat_a<<<g, b, 0, stream>>>(pred_embs, DIN, DIN, rel_table, DW,
                                            rels + 1, 3, ch0, T_N, mp, 296, S1);
        GK2<128, 128>(stream, S1, mp, S3A, DIN, 296, mv, bf_rel, 1,
                      nullptr, 0, S2, mp);
        GX<64, 64>(stream, S2, mp, S3B, HH_, 256, mv, nullptr, 0,
                   PP + (size_t)ch0 * HH_, HH_, nullptr, 0,
                   nullptr, nullptr, nullptr);
    }

    // ================= 5 conv layers =================
    for (int L = 0; L < 5; L++) {
        const float* bb1a = (L == 0) ? b1a : (bs1a + (size_t)(L - 1) * HH_);
        const float* w1b  = (L == 0) ? W1b : (Ws1b + (size_t)(L - 1) * HH_ * 1536);
        const float* bb1b = (L == 0) ? b1b : (bs1b + (size_t)(L - 1) * 1536);
        const float* w2a  = (L == 0) ? W2a : (Ws2a + (size_t)(L - 1) * HH_ * HH_);
        const float* bb2a = (L == 0) ? b2a : (bs2a + (size_t)(L - 1) * HH_);
        const float* w2b  = (L == 0) ? W2b : (Ws2b + (size_t)(L - 1) * HH_ * DG);
        const float* bb2b = (L == 0) ? b2b : (bs2b + (size_t)(L - 1) * DG);

        if (L > 0) {
            const float* w1a = Ws1a + (size_t)(L - 1) * 3 * HH_ * HH_;
            SB(stream, w1a, HH_, HH_, 64, S3B);                       // top
            SB(stream, w1a + (size_t)2 * HH_ * HH_, HH_, HH_, 64, S3C); // bot
            GX<64, 64>(stream, OVp, 2048, S3B, HH_, 64, O_N, nullptr, 0,
                       P1, HH_, nullptr, 0, S3C, P2, nullptr);
            SB(stream, w1a + (size_t)HH_ * HH_, HH_, HH_, 64, S3B);   // mid
            GX<64, 64>(stream, PVp, 6016, S3B, HH_, 64, T_N, nullptr, 0,
                       PP, HH_, nullptr, 0, nullptr, nullptr, nullptr);
        }

        // edge combine -> TT planes
        {
            dim3 g(24, 64), b(256);
            edge_planes<<<g, b, 0, stream>>>(PP, P1, P2, rels, bb1a, 6016, TTp);
        }
        // t2 = relu(TT @ W1b + b1b) — 564 blocks, 2 resident/CU (74 KB LDS)
        SB(stream, w1b, HH_, 1536, 64, S3C);
        GX<128, 128>(stream, TTp, 6016, S3C, 1536, 64, T_N, bb1b, 1,
                     T2, 1536, nullptr, 0, nullptr, nullptr, nullptr);
        // pooling
        hipMemsetAsync(PO, 0, (size_t)O_N * HH_ * sizeof(float), stream);
        hipLaunchKernelGGL(scatter_pool, dim3(T_N), dim3(256), 0, stream, T2, rels, PO);
        {
            dim3 g(8, 64), b(256);
            pool_planes<<<g, b, 0, stream>>>(PO, CNT, 2048, PLp);
        }
        // obj MLP2
        SB(stream, w2a, HH_, HH_, 64, S3B);
        GX<64, 64>(stream, PLp, 2048, S3B, HH_, 64, O_N, bb2a, 1,
                   nullptr, 0, Hp, 2048, nullptr, nullptr, nullptr);
        SB(stream, w2b, HH_, DG, 64, S3C);
        if (L < 4) {
            GX<64, 64>(stream, Hp, 2048, S3C, DG, 64, O_N, bb2b, 1,
                       nullptr, 0, OVp, 2048, nullptr, nullptr, nullptr);
            dim3 g(24, 64), b(256);
            predcopy_planes<<<g, b, 0, stream>>>(T2, 6016, PVp);
        } else {
            GX<64, 64>(stream, Hp, 2048, S3C, DG, 64, O_N, bb2b, 1,
                       out, DG, nullptr, 0, nullptr, nullptr, nullptr);
            hipLaunchKernelGGL(predcopy_f32, dim3((T_N * HH_ / 4 + 255) / 256),
                               dim3(256), 0, stream, T2, out + (size_t)O_N * DG);
        }
    }
}